// Round 4
// baseline (2275.570 us; speedup 1.0000x reference)
//
#include <hip/hip_runtime.h>
#include <math.h>

#ifndef M_PI
#define M_PI 3.14159265358979323846
#endif

#define HW 16384

// ---------- swizzled LDS addressing for 128x128 f32 plane tiles ----------
// logical (r,c) -> physical r*128 + 4*((c>>2) ^ ((r>>3)&7)) + (c&3)
__device__ __forceinline__ int swz4(int r, int c4) {
  return (r << 7) + ((((c4 >> 2) ^ ((r >> 3) & 7)) << 2));
}

// ---------- tables: cosine map (H==W==128) and decay exponent ----------
__global__ void k0_tables(float* __restrict__ cc, float* __restrict__ ee) {
  int gid = blockIdx.x * 256 + threadIdx.x;   // 16384
  int n = gid >> 7, m = gid & 127;
  double v = cos((double)n * ((double)m + 0.5) * (M_PI / 128.0)) * sqrt(2.0 / 128.0);
  if (n == 0) v *= 0.70710678118654752440;
  cc[gid] = (float)v;
  double wn = (double)n * (M_PI / 128.0), wm = (double)m * (M_PI / 128.0);
  ee[gid] = (float)(wn * wn + wm * wm);
}

// ---------- generic weight transpose: src[D][C] -> dst[C][D] ----------
__global__ void k_wt(const float* __restrict__ src, float* __restrict__ dst, int D, int C) {
  int gid = blockIdx.x * 256 + threadIdx.x;
  if (gid >= D * C) return;
  int d = gid / C, c = gid % C;
  dst[c * D + d] = src[gid];
}

// ---------- K2: fused depthwise 3x3 conv + lin GEMM (K=96 -> N=192 split) ----------
__global__ __launch_bounds__(256) void k2_conv_lin(
    const float* __restrict__ x, const float* __restrict__ dw_w,
    const float* __restrict__ dw_b, const float* __restrict__ linT,
    const float* __restrict__ lin_b, float* __restrict__ x1p, float* __restrict__ z) {
  int gid = blockIdx.x * 256 + threadIdx.x;   // 131072 = B*HW
  int b = gid >> 14, hw = gid & 16383;
  int h = hw >> 7, w = hw & 127;
  const float* xb = x + (size_t)b * 96 * HW + hw;
  const bool tp = h > 0, bt = h < 127, lf = w > 0, rt = w < 127;

  for (int half = 0; half < 2; ++half) {
    float acc[96];
#pragma unroll
    for (int d = 0; d < 96; ++d) acc[d] = lin_b[half * 96 + d];
    for (int c = 0; c < 96; ++c) {
      const float* p = xb + (size_t)c * HW;
      float v   = p[0];
      float vl  = lf ? p[-1] : 0.f;
      float vr  = rt ? p[1] : 0.f;
      float vt  = tp ? p[-128] : 0.f;
      float vb  = bt ? p[128] : 0.f;
      float vtl = (tp && lf) ? p[-129] : 0.f;
      float vtr = (tp && rt) ? p[-127] : 0.f;
      float vbl = (bt && lf) ? p[127] : 0.f;
      float vbr = (bt && rt) ? p[129] : 0.f;
      const float* wc = dw_w + c * 9;
      float conv = vtl * wc[0] + vt * wc[1] + vtr * wc[2]
                 + vl  * wc[3] + v  * wc[4] + vr  * wc[5]
                 + vbl * wc[6] + vb * wc[7] + vbr * wc[8] + dw_b[c];
      const float* wr = linT + c * 192 + half * 96;
#pragma unroll
      for (int d = 0; d < 96; ++d) acc[d] = fmaf(conv, wr[d], acc[d]);
    }
    if (half == 0) {
#pragma unroll
      for (int d = 0; d < 96; ++d) x1p[(size_t)(b * 96 + d) * HW + hw] = acc[d];
    } else {
      float* zp = z + (size_t)gid * 96;
#pragma unroll
      for (int d = 0; d < 96; d += 4)
        *(float4*)&zp[d] = make_float4(acc[d], acc[d + 1], acc[d + 2], acc[d + 3]);
    }
  }
}

// ---------- K3: outline_feat transpose to plane-major + mean over B ----------
__global__ __launch_bounds__(256) void k3_transpose_mean(
    const float* __restrict__ of, float* __restrict__ ofp, float* __restrict__ cmU) {
  __shared__ float tile[64 * 97];
  int hw0 = blockIdx.x * 64;
  int tid = threadIdx.x;
  float sum[24];
#pragma unroll
  for (int t = 0; t < 24; ++t) sum[t] = 0.f;
  for (int b = 0; b < 8; ++b) {
    __syncthreads();
#pragma unroll
    for (int t = 0; t < 24; ++t) {
      int l = tid + t * 256;
      int r = l / 96, c0 = l % 96;
      tile[r * 97 + c0] = of[((size_t)b * 16384 + hw0 + r) * 96 + c0];
    }
    __syncthreads();
#pragma unroll
    for (int t = 0; t < 24; ++t) {
      int l = tid + t * 256;
      int c0 = l >> 6, r = l & 63;
      float v = tile[r * 97 + c0];
      sum[t] += v;
      ofp[(size_t)(b * 96 + c0) * HW + hw0 + r] = v;
    }
  }
#pragma unroll
  for (int t = 0; t < 24; ++t) {
    int l = tid + t * 256;
    int c0 = l >> 6, r = l & 63;
    cmU[(size_t)c0 * HW + hw0 + r] = sum[t] * 0.125f;
  }
}

// ---------- K3b: k = relu((freq+otm)@k_w^T + k_b); P1 = exp(-e*k) ----------
__global__ __launch_bounds__(256) void k3b_kgemm(
    const float* __restrict__ fe, const float* __restrict__ otm,
    const float* __restrict__ kT, const float* __restrict__ kb,
    const float* __restrict__ ee, float* __restrict__ P1) {
  int row = blockIdx.x * 256 + threadIdx.x;
  float acc[96];
#pragma unroll
  for (int d = 0; d < 96; ++d) acc[d] = kb[d];
  for (int c = 0; c < 96; ++c) {
    float a = fe[(size_t)row * 96 + c] + otm[(size_t)c * HW + row];
    const float* wr = kT + c * 96;
#pragma unroll
    for (int d = 0; d < 96; ++d) acc[d] = fmaf(a, wr[d], acc[d]);
  }
  float er = ee[row];
#pragma unroll
  for (int d = 0; d < 96; ++d)
    P1[(size_t)d * HW + row] = expf(-er * fmaxf(acc[d], 0.f));
}

// ---------- fused per-plane heat pass: Y = Cc^T ( P . (Cc U Cc^T) ) Cc ----------
// Primitive computes OUT[i][j] = sum_k A[k][i] * B[k][j] (all row-reads).
template <bool A_PANEL, bool PANEL_T, bool OUT_T>
__device__ __forceinline__ void mm_step(const float* __restrict__ cc,
                                        const float* __restrict__ Afull,
                                        const float* __restrict__ Bfull,
                                        float* Pan, float* OUT, int tid) {
  const int ty = tid >> 4, tx = tid & 15;
  const int i0 = ty << 3, j0 = tx << 3;
  float acc[8][8];
#pragma unroll
  for (int i = 0; i < 8; ++i)
#pragma unroll
    for (int j = 0; j < 8; ++j) acc[i][j] = 0.f;

  for (int k0 = 0; k0 < 128; k0 += 16) {
    __syncthreads();
    if constexpr (PANEL_T) {   // Pan[kk][x] = cc[x][k0+kk]
#pragma unroll
      for (int rep = 0; rep < 2; ++rep) {
        int xx = (tid >> 2) + rep * 64;
        int kk4 = (tid & 3) << 2;
        float4 v = *(const float4*)&cc[xx * 128 + k0 + kk4];
        Pan[(kk4 + 0) * 132 + xx] = v.x;
        Pan[(kk4 + 1) * 132 + xx] = v.y;
        Pan[(kk4 + 2) * 132 + xx] = v.z;
        Pan[(kk4 + 3) * 132 + xx] = v.w;
      }
    } else {                   // Pan[kk][x] = cc[k0+kk][x]
#pragma unroll
      for (int rep = 0; rep < 2; ++rep) {
        int q = tid + rep * 256;
        int kk = q >> 5, c4 = (q & 31) << 2;
        *(float4*)&Pan[kk * 132 + c4] = *(const float4*)&cc[(k0 + kk) * 128 + c4];
      }
    }
    __syncthreads();
#pragma unroll
    for (int kk = 0; kk < 16; ++kk) {
      const int k = k0 + kk;
      float a[8], bv[8];
      if constexpr (A_PANEL) {
        *(float4*)&a[0] = *(const float4*)&Pan[kk * 132 + i0];
        *(float4*)&a[4] = *(const float4*)&Pan[kk * 132 + i0 + 4];
        *(float4*)&bv[0] = *(const float4*)&Bfull[swz4(k, j0)];
        *(float4*)&bv[4] = *(const float4*)&Bfull[swz4(k, j0 + 4)];
      } else {
        *(float4*)&a[0] = *(const float4*)&Afull[swz4(k, i0)];
        *(float4*)&a[4] = *(const float4*)&Afull[swz4(k, i0 + 4)];
        *(float4*)&bv[0] = *(const float4*)&Pan[kk * 132 + j0];
        *(float4*)&bv[4] = *(const float4*)&Pan[kk * 132 + j0 + 4];
      }
#pragma unroll
      for (int i = 0; i < 8; ++i)
#pragma unroll
        for (int j = 0; j < 8; ++j) acc[i][j] = fmaf(a[i], bv[j], acc[i][j]);
    }
  }
  if constexpr (OUT_T) {
#pragma unroll
    for (int j = 0; j < 8; ++j) {
      *(float4*)&OUT[swz4(j0 + j, i0)] =
          make_float4(acc[0][j], acc[1][j], acc[2][j], acc[3][j]);
      *(float4*)&OUT[swz4(j0 + j, i0 + 4)] =
          make_float4(acc[4][j], acc[5][j], acc[6][j], acc[7][j]);
    }
  } else {
#pragma unroll
    for (int i = 0; i < 8; ++i) {
      *(float4*)&OUT[swz4(i0 + i, j0)] =
          make_float4(acc[i][0], acc[i][1], acc[i][2], acc[i][3]);
      *(float4*)&OUT[swz4(i0 + i, j0 + 4)] =
          make_float4(acc[i][4], acc[i][5], acc[i][6], acc[i][7]);
    }
  }
}

__global__ __launch_bounds__(256) void heat_kernel(
    float* bufA, float* bufB, const float* __restrict__ P,
    const float* __restrict__ cc, int Ceff) {
  __shared__ float Xs[128 * 128];
  __shared__ float Ys[128 * 128];
  __shared__ float Pan[16 * 132];
  int tid = threadIdx.x;
  int plane = blockIdx.x;
  int b = plane / Ceff, c = plane % Ceff;
  float* Ug = (c < 96) ? (bufA + (size_t)(b * 96 + c) * HW)
                       : (bufB + (size_t)(b * 96 + (c - 96)) * HW);
  const float* Pp = P + (size_t)c * HW;

#pragma unroll
  for (int t = 0; t < 16; ++t) {           // load U (swizzled into Xs)
    int q = tid + t * 256;                 // float4 index, 4096 total
    int r = q >> 5, c4 = (q & 31) << 2;
    *(float4*)&Xs[swz4(r, c4)] = *(const float4*)&Ug[(r << 7) + c4];
  }
  // step1: T = Cc*U        (A = panelT, B = Xs)  -> Ys holds T^T
  mm_step<true, true, true>(cc, nullptr, Xs, Pan, Ys, tid);
  // step2: S = T*Cc^T      (A = Ys(T^T), B = panelT) -> Xs holds S
  mm_step<false, true, false>(cc, Ys, nullptr, Pan, Xs, tid);
  __syncthreads();
#pragma unroll
  for (int t = 0; t < 64; ++t) {           // decay multiply S *= P
    int q = tid + t * 256;
    int r = q >> 7, cx = q & 127;
    int idx = (r << 7) + (((((cx >> 2) ^ ((r >> 3) & 7)) << 2)) | (cx & 3));
    Xs[idx] *= Pp[q];
  }
  // step3: T2 = Cc^T*S     (A = panelR, B = Xs) -> Ys holds T2^T
  mm_step<true, false, true>(cc, nullptr, Xs, Pan, Ys, tid);
  // step4: Y = T2*Cc       (A = Ys(T2^T), B = panelR) -> Xs holds Y
  mm_step<false, false, false>(cc, Ys, nullptr, Pan, Xs, tid);
  __syncthreads();
#pragma unroll
  for (int t = 0; t < 16; ++t) {           // store in place
    int q = tid + t * 256;
    int r = q >> 5, c4 = (q & 31) << 2;
    *(float4*)&Ug[(r << 7) + c4] = *(float4*)&Xs[swz4(r, c4)];
  }
}

// ---------- K5: catmean lower half = mean_b(y1) ----------
__global__ void k5_mean(const float* __restrict__ x1p, float* __restrict__ cmL) {
  int idx = blockIdx.x * 256 + threadIdx.x;   // < 96*HW, layout [c][s]
  int c = idx >> 14, s = idx & 16383;
  float sum = 0.f;
#pragma unroll
  for (int b = 0; b < 8; ++b) sum += x1p[(size_t)(b * 96 + c) * HW + s];
  cmL[idx] = sum * 0.125f;
}

// ---------- K6: skfeat = catmean @ lin2_w^T + lin2_b (c-major in/out) ----------
__global__ __launch_bounds__(256) void k6_skf(
    const float* __restrict__ cm, const float* __restrict__ w2T,
    const float* __restrict__ b2, float* __restrict__ skf) {
  int row = blockIdx.x * 256 + threadIdx.x;
  for (int half = 0; half < 2; ++half) {
    float acc[96];
#pragma unroll
    for (int d = 0; d < 96; ++d) acc[d] = b2[half * 96 + d];
    for (int k = 0; k < 192; ++k) {
      float a = cm[(size_t)k * HW + row];
      const float* wr = w2T + k * 192 + half * 96;
#pragma unroll
      for (int d = 0; d < 96; ++d) acc[d] = fmaf(a, wr[d], acc[d]);
    }
#pragma unroll
    for (int d = 0; d < 96; ++d) skf[(size_t)(half * 96 + d) * HW + row] = acc[d];
  }
}

// ---------- K7: k2 = relu(skf@k2_w^T + k2_b); P2 = exp(-e*k2) ----------
__global__ __launch_bounds__(256) void k7_k2(
    const float* __restrict__ skf, const float* __restrict__ w2T,
    const float* __restrict__ b2, const float* __restrict__ ee,
    float* __restrict__ P2) {
  int row = blockIdx.x * 256 + threadIdx.x;
  float er = ee[row];
  for (int half = 0; half < 2; ++half) {
    float acc[96];
#pragma unroll
    for (int d = 0; d < 96; ++d) acc[d] = b2[half * 96 + d];
    for (int k = 0; k < 192; ++k) {
      float a = skf[(size_t)k * HW + row];
      const float* wr = w2T + k * 192 + half * 96;
#pragma unroll
      for (int d = 0; d < 96; ++d) acc[d] = fmaf(a, wr[d], acc[d]);
    }
#pragma unroll
    for (int d = 0; d < 96; ++d)
      P2[(size_t)(half * 96 + d) * HW + row] = expf(-er * fmaxf(acc[d], 0.f));
  }
}

// ---------- K9: lin3 + LayerNorm + *silu(z) + out GEMM + NCHW write ----------
__global__ __launch_bounds__(256) void k9_epilogue(
    const float* __restrict__ y1, const float* __restrict__ y2,
    const float* __restrict__ z,
    const float* __restrict__ lin3T, const float* __restrict__ lin3b,
    const float* __restrict__ lng, const float* __restrict__ lnb,
    const float* __restrict__ outT, const float* __restrict__ outb,
    float* __restrict__ out) {
  int gid = blockIdx.x * 256 + threadIdx.x;
  int b = gid >> 14, hw = gid & 16383;
  float t[96];
#pragma unroll
  for (int d = 0; d < 96; ++d) t[d] = lin3b[d];
  for (int k = 0; k < 96; ++k) {
    float a = y1[(size_t)(b * 96 + k) * HW + hw];
    const float* wr = lin3T + k * 96;
#pragma unroll
    for (int d = 0; d < 96; ++d) t[d] = fmaf(a, wr[d], t[d]);
  }
  for (int k = 0; k < 96; ++k) {
    float a = y2[(size_t)(b * 96 + k) * HW + hw];
    const float* wr = lin3T + (96 + k) * 96;
#pragma unroll
    for (int d = 0; d < 96; ++d) t[d] = fmaf(a, wr[d], t[d]);
  }
  float mu = 0.f;
#pragma unroll
  for (int d = 0; d < 96; ++d) mu += t[d];
  mu *= (1.f / 96.f);
  float var = 0.f;
#pragma unroll
  for (int d = 0; d < 96; ++d) { float dv = t[d] - mu; var = fmaf(dv, dv, var); }
  var *= (1.f / 96.f);
  float inv = rsqrtf(var + 1e-5f);
  const float* zp = z + (size_t)gid * 96;
#pragma unroll
  for (int d = 0; d < 96; ++d) {
    float zv = zp[d];
    float sil = zv / (1.f + expf(-zv));
    t[d] = ((t[d] - mu) * inv * lng[d] + lnb[d]) * sil;
  }
  for (int half = 0; half < 2; ++half) {
    float acc[48];
#pragma unroll
    for (int j = 0; j < 48; ++j) acc[j] = outb[half * 48 + j];
#pragma unroll
    for (int c2 = 0; c2 < 96; ++c2) {
      float a = t[c2];
      const float* wr = outT + c2 * 96 + half * 48;
#pragma unroll
      for (int j = 0; j < 48; ++j) acc[j] = fmaf(a, wr[j], acc[j]);
    }
#pragma unroll
    for (int j = 0; j < 48; ++j)
      out[(size_t)(b * 96 + half * 48 + j) * HW + hw] = acc[j];
  }
}

extern "C" void kernel_launch(void* const* d_in, const int* in_sizes, int n_in,
                              void* d_out, int out_size, void* d_ws, size_t ws_size,
                              hipStream_t stream) {
  const float* x      = (const float*)d_in[0];
  const float* fe     = (const float*)d_in[1];
  const float* of     = (const float*)d_in[2];
  const float* dw_w   = (const float*)d_in[3];
  const float* dw_b   = (const float*)d_in[4];
  const float* lin_w  = (const float*)d_in[5];
  const float* lin_b  = (const float*)d_in[6];
  const float* k_w    = (const float*)d_in[7];
  const float* k_b    = (const float*)d_in[8];
  const float* lin2_w = (const float*)d_in[9];
  const float* lin2_b = (const float*)d_in[10];
  const float* k2_w   = (const float*)d_in[11];
  const float* k2_b   = (const float*)d_in[12];
  const float* lin3_w = (const float*)d_in[13];
  const float* lin3_b = (const float*)d_in[14];
  const float* ln_g   = (const float*)d_in[15];
  const float* ln_b   = (const float*)d_in[16];
  const float* out_w  = (const float*)d_in[17];
  const float* out_b  = (const float*)d_in[18];
  float* out = (float*)d_out;

  float* ws    = (float*)d_ws;
  float* x1p   = ws;                      // [B][96][HW]  (x1 -> y1 -> y2 low)
  float* z     = x1p   + 12582912;        // [B][HW][96]
  float* ofp   = z     + 12582912;        // [B][96][HW]  (outline planes -> y2 high)
  float* cm    = ofp   + 12582912;        // [192][HW] catmean (c-major)
  float* skf   = cm    + 3145728;         // [192][HW]
  float* P1    = skf   + 3145728;         // [96][HW]
  float* P2    = P1    + 1572864;         // [192][HW]
  float* cc    = P2    + 3145728;         // [128][128]
  float* ee    = cc    + 16384;           // [128][128]
  float* linT  = ee    + 16384;           // [96][192]
  float* kT    = linT  + 18432;           // [96][96]
  float* lin2T = kT    + 9216;            // [192][192]
  float* k2T   = lin2T + 36864;           // [192][192]
  float* lin3T = k2T   + 36864;           // [192][96]
  float* outT  = lin3T + 18432;           // [96][96]
  (void)in_sizes; (void)n_in; (void)out_size; (void)ws_size;

  k0_tables<<<64, 256, 0, stream>>>(cc, ee);
  k_wt<<<72, 256, 0, stream>>>(lin_w, linT, 192, 96);
  k_wt<<<36, 256, 0, stream>>>(k_w, kT, 96, 96);
  k_wt<<<144, 256, 0, stream>>>(lin2_w, lin2T, 192, 192);
  k_wt<<<144, 256, 0, stream>>>(k2_w, k2T, 192, 192);
  k_wt<<<72, 256, 0, stream>>>(lin3_w, lin3T, 96, 192);
  k_wt<<<36, 256, 0, stream>>>(out_w, outT, 96, 96);

  k2_conv_lin<<<512, 256, 0, stream>>>(x, dw_w, dw_b, linT, lin_b, x1p, z);
  k3_transpose_mean<<<256, 256, 0, stream>>>(of, ofp, cm + (size_t)96 * HW);
  k3b_kgemm<<<64, 256, 0, stream>>>(fe, cm + (size_t)96 * HW, kT, k_b, ee, P1);
  heat_kernel<<<768, 256, 0, stream>>>(x1p, x1p, P1, cc, 96);
  k5_mean<<<6144, 256, 0, stream>>>(x1p, cm);
  k6_skf<<<64, 256, 0, stream>>>(cm, lin2T, lin2_b, skf);
  k7_k2<<<64, 256, 0, stream>>>(skf, k2T, k2_b, ee, P2);
  heat_kernel<<<1536, 256, 0, stream>>>(x1p, ofp, P2, cc, 192);
  k9_epilogue<<<512, 256, 0, stream>>>(x1p, ofp, z, lin3T, lin3_b, ln_g, ln_b,
                                       outT, out_b, out);
}

// Round 5
// 1049.080 us; speedup vs baseline: 2.1691x; 2.1691x over previous
//
#include <hip/hip_runtime.h>
#include <math.h>

#ifndef M_PI
#define M_PI 3.14159265358979323846
#endif

#define HW 16384

// ---------- swizzled LDS addressing for 128x128 f32 plane tiles ----------
__device__ __forceinline__ int swz4(int r, int c4) {
  return (r << 7) + ((((c4 >> 2) ^ ((r >> 3) & 7)) << 2));
}

// ---------- tables: cosine map (H==W==128) and decay exponent ----------
__global__ void k0_tables(float* __restrict__ cc, float* __restrict__ ee) {
  int gid = blockIdx.x * 256 + threadIdx.x;   // 16384
  int n = gid >> 7, m = gid & 127;
  double v = cos((double)n * ((double)m + 0.5) * (M_PI / 128.0)) * sqrt(2.0 / 128.0);
  if (n == 0) v *= 0.70710678118654752440;
  cc[gid] = (float)v;
  double wn = (double)n * (M_PI / 128.0), wm = (double)m * (M_PI / 128.0);
  ee[gid] = (float)(wn * wn + wm * wm);
}

// ---------- generic weight transpose: src[D][C] -> dst[C][D] ----------
__global__ void k_wt(const float* __restrict__ src, float* __restrict__ dst, int D, int C) {
  int gid = blockIdx.x * 256 + threadIdx.x;
  if (gid >= D * C) return;
  int d = gid / C, c = gid % C;
  dst[c * D + d] = src[gid];
}

// ---------- fe transpose: [HW][96] -> [96][HW] ----------
__global__ __launch_bounds__(256) void k_tfe(const float* __restrict__ fe,
                                             float* __restrict__ fet) {
  __shared__ float tile[64 * 97];
  int hw0 = blockIdx.x * 64;
  int tid = threadIdx.x;
#pragma unroll
  for (int t = 0; t < 24; ++t) {
    int l = tid + t * 256;
    int r = l / 96, c0 = l % 96;
    tile[r * 97 + c0] = fe[((size_t)hw0 + r) * 96 + c0];
  }
  __syncthreads();
#pragma unroll
  for (int t = 0; t < 24; ++t) {
    int l = tid + t * 256;
    int c0 = l >> 6, r = l & 63;
    fet[(size_t)c0 * HW + hw0 + r] = tile[r * 97 + c0];
  }
}

// ---------- KC: depthwise 3x3 conv, float4 per thread, plane-major out ----------
__global__ __launch_bounds__(256) void kconv(
    const float* __restrict__ x, const float* __restrict__ dw_w,
    const float* __restrict__ dw_b, float* __restrict__ xc) {
  int gid = blockIdx.x * 256 + threadIdx.x;   // B*96*4096 = 3145728
  int p = gid >> 12;                          // plane b*96+c
  int q = gid & 4095;
  int h = q >> 5, w4 = (q & 31) << 2;
  int c = p % 96;
  const float* pw = dw_w + c * 9;
  const float* row = x + (size_t)p * HW + h * 128 + w4;
  bool tp = h > 0, bt = h < 127, lf = w4 > 0, rt = w4 < 124;
  float4 t_, m_, b_;
  float tl, tr, ml, mr, bl, br;
  m_ = *(const float4*)row;
  ml = lf ? row[-1] : 0.f;
  mr = rt ? row[4] : 0.f;
  if (tp) {
    t_ = *(const float4*)(row - 128);
    tl = lf ? row[-129] : 0.f;
    tr = rt ? row[-124] : 0.f;
  } else { t_ = make_float4(0.f, 0.f, 0.f, 0.f); tl = tr = 0.f; }
  if (bt) {
    b_ = *(const float4*)(row + 128);
    bl = lf ? row[127] : 0.f;
    br = rt ? row[132] : 0.f;
  } else { b_ = make_float4(0.f, 0.f, 0.f, 0.f); bl = br = 0.f; }
  float w0 = pw[0], w1 = pw[1], w2 = pw[2], w3 = pw[3], w4w = pw[4],
        w5 = pw[5], w6 = pw[6], w7 = pw[7], w8 = pw[8];
  float bias = dw_b[c];
  float4 o;
  o.x = tl * w0 + t_.x * w1 + t_.y * w2 + ml * w3 + m_.x * w4w + m_.y * w5 + bl * w6 + b_.x * w7 + b_.y * w8 + bias;
  o.y = t_.x * w0 + t_.y * w1 + t_.z * w2 + m_.x * w3 + m_.y * w4w + m_.z * w5 + b_.x * w6 + b_.y * w7 + b_.z * w8 + bias;
  o.z = t_.y * w0 + t_.z * w1 + t_.w * w2 + m_.y * w3 + m_.z * w4w + m_.w * w5 + b_.y * w6 + b_.z * w7 + b_.w * w8 + bias;
  o.w = t_.z * w0 + t_.w * w1 + tr * w2 + m_.z * w3 + m_.w * w4w + mr * w5 + b_.z * w6 + b_.w * w7 + br * w8 + bias;
  *(float4*)(xc + (size_t)p * HW + h * 128 + w4) = o;
}

// ---------- KL: lin GEMM  [B*HW,96] @ [96,192]; wave owns 48-wide N-chunk ----------
__global__ __launch_bounds__(256) void klin(
    const float* __restrict__ xc, const float* __restrict__ linT,
    const float* __restrict__ lin_b, float* __restrict__ x1p, float* __restrict__ z) {
  int tid = threadIdx.x;
  int lane = tid & 63;
  int n0 = __builtin_amdgcn_readfirstlane((tid >> 6) * 48);
  int gpos = blockIdx.x * 64 + lane;          // 2048 blocks
  int b = gpos >> 14, hw = gpos & 16383;
  float acc[48];
#pragma unroll
  for (int j = 0; j < 48; ++j) acc[j] = lin_b[n0 + j];
#pragma unroll 4
  for (int c = 0; c < 96; ++c) {
    float a = xc[(size_t)(b * 96 + c) * HW + hw];
    const float* wr = linT + c * 192 + n0;
#pragma unroll
    for (int j = 0; j < 48; ++j) acc[j] = fmaf(a, wr[j], acc[j]);
  }
  if (n0 < 96) {
#pragma unroll
    for (int j = 0; j < 48; ++j)
      x1p[(size_t)(b * 96 + n0 + j) * HW + hw] = acc[j];
  } else {
    float* zp = z + (size_t)gpos * 96 + (n0 - 96);
#pragma unroll
    for (int j = 0; j < 48; j += 4)
      *(float4*)&zp[j] = make_float4(acc[j], acc[j + 1], acc[j + 2], acc[j + 3]);
  }
}

// ---------- K3: outline_feat transpose to plane-major + mean over B ----------
__global__ __launch_bounds__(256) void k3_transpose_mean(
    const float* __restrict__ of, float* __restrict__ ofp, float* __restrict__ cmU) {
  __shared__ float tile[64 * 97];
  int hw0 = blockIdx.x * 64;
  int tid = threadIdx.x;
  float sum[24];
#pragma unroll
  for (int t = 0; t < 24; ++t) sum[t] = 0.f;
  for (int b = 0; b < 8; ++b) {
    __syncthreads();
#pragma unroll
    for (int t = 0; t < 24; ++t) {
      int l = tid + t * 256;
      int r = l / 96, c0 = l % 96;
      tile[r * 97 + c0] = of[((size_t)b * 16384 + hw0 + r) * 96 + c0];
    }
    __syncthreads();
#pragma unroll
    for (int t = 0; t < 24; ++t) {
      int l = tid + t * 256;
      int c0 = l >> 6, r = l & 63;
      float v = tile[r * 97 + c0];
      sum[t] += v;
      ofp[(size_t)(b * 96 + c0) * HW + hw0 + r] = v;
    }
  }
#pragma unroll
  for (int t = 0; t < 24; ++t) {
    int l = tid + t * 256;
    int c0 = l >> 6, r = l & 63;
    cmU[(size_t)c0 * HW + hw0 + r] = sum[t] * 0.125f;
  }
}

// ---------- K3b: k = relu((fet+otm)@k_w^T + k_b); P1 = exp(-e*k) ----------
__global__ __launch_bounds__(256) void k3b_kgemm(
    const float* __restrict__ fet, const float* __restrict__ otm,
    const float* __restrict__ kT, const float* __restrict__ kb,
    const float* __restrict__ ee, float* __restrict__ P1) {
  int tid = threadIdx.x;
  int lane = tid & 63;
  int n0 = __builtin_amdgcn_readfirstlane((tid >> 6) * 24);
  int row = blockIdx.x * 64 + lane;           // 256 blocks
  float acc[24];
#pragma unroll
  for (int j = 0; j < 24; ++j) acc[j] = kb[n0 + j];
#pragma unroll 4
  for (int c = 0; c < 96; ++c) {
    float a = fet[(size_t)c * HW + row] + otm[(size_t)c * HW + row];
    const float* wr = kT + c * 96 + n0;
#pragma unroll
    for (int j = 0; j < 24; ++j) acc[j] = fmaf(a, wr[j], acc[j]);
  }
  float er = ee[row];
#pragma unroll
  for (int j = 0; j < 24; ++j)
    P1[(size_t)(n0 + j) * HW + row] = expf(-er * fmaxf(acc[j], 0.f));
}

// ---------- fused per-plane heat pass (unchanged) ----------
template <bool A_PANEL, bool PANEL_T, bool OUT_T>
__device__ __forceinline__ void mm_step(const float* __restrict__ cc,
                                        const float* __restrict__ Afull,
                                        const float* __restrict__ Bfull,
                                        float* Pan, float* OUT, int tid) {
  const int ty = tid >> 4, tx = tid & 15;
  const int i0 = ty << 3, j0 = tx << 3;
  float acc[8][8];
#pragma unroll
  for (int i = 0; i < 8; ++i)
#pragma unroll
    for (int j = 0; j < 8; ++j) acc[i][j] = 0.f;

  for (int k0 = 0; k0 < 128; k0 += 16) {
    __syncthreads();
    if constexpr (PANEL_T) {
#pragma unroll
      for (int rep = 0; rep < 2; ++rep) {
        int xx = (tid >> 2) + rep * 64;
        int kk4 = (tid & 3) << 2;
        float4 v = *(const float4*)&cc[xx * 128 + k0 + kk4];
        Pan[(kk4 + 0) * 132 + xx] = v.x;
        Pan[(kk4 + 1) * 132 + xx] = v.y;
        Pan[(kk4 + 2) * 132 + xx] = v.z;
        Pan[(kk4 + 3) * 132 + xx] = v.w;
      }
    } else {
#pragma unroll
      for (int rep = 0; rep < 2; ++rep) {
        int q = tid + rep * 256;
        int kk = q >> 5, c4 = (q & 31) << 2;
        *(float4*)&Pan[kk * 132 + c4] = *(const float4*)&cc[(k0 + kk) * 128 + c4];
      }
    }
    __syncthreads();
#pragma unroll
    for (int kk = 0; kk < 16; ++kk) {
      const int k = k0 + kk;
      float a[8], bv[8];
      if constexpr (A_PANEL) {
        *(float4*)&a[0] = *(const float4*)&Pan[kk * 132 + i0];
        *(float4*)&a[4] = *(const float4*)&Pan[kk * 132 + i0 + 4];
        *(float4*)&bv[0] = *(const float4*)&Bfull[swz4(k, j0)];
        *(float4*)&bv[4] = *(const float4*)&Bfull[swz4(k, j0 + 4)];
      } else {
        *(float4*)&a[0] = *(const float4*)&Afull[swz4(k, i0)];
        *(float4*)&a[4] = *(const float4*)&Afull[swz4(k, i0 + 4)];
        *(float4*)&bv[0] = *(const float4*)&Pan[kk * 132 + j0];
        *(float4*)&bv[4] = *(const float4*)&Pan[kk * 132 + j0 + 4];
      }
#pragma unroll
      for (int i = 0; i < 8; ++i)
#pragma unroll
        for (int j = 0; j < 8; ++j) acc[i][j] = fmaf(a[i], bv[j], acc[i][j]);
    }
  }
  if constexpr (OUT_T) {
#pragma unroll
    for (int j = 0; j < 8; ++j) {
      *(float4*)&OUT[swz4(j0 + j, i0)] =
          make_float4(acc[0][j], acc[1][j], acc[2][j], acc[3][j]);
      *(float4*)&OUT[swz4(j0 + j, i0 + 4)] =
          make_float4(acc[4][j], acc[5][j], acc[6][j], acc[7][j]);
    }
  } else {
#pragma unroll
    for (int i = 0; i < 8; ++i) {
      *(float4*)&OUT[swz4(i0 + i, j0)] =
          make_float4(acc[i][0], acc[i][1], acc[i][2], acc[i][3]);
      *(float4*)&OUT[swz4(i0 + i, j0 + 4)] =
          make_float4(acc[i][4], acc[i][5], acc[i][6], acc[i][7]);
    }
  }
}

__global__ __launch_bounds__(256) void heat_kernel(
    float* bufA, float* bufB, const float* __restrict__ P,
    const float* __restrict__ cc, int Ceff) {
  __shared__ float Xs[128 * 128];
  __shared__ float Ys[128 * 128];
  __shared__ float Pan[16 * 132];
  int tid = threadIdx.x;
  int plane = blockIdx.x;
  int b = plane / Ceff, c = plane % Ceff;
  float* Ug = (c < 96) ? (bufA + (size_t)(b * 96 + c) * HW)
                       : (bufB + (size_t)(b * 96 + (c - 96)) * HW);
  const float* Pp = P + (size_t)c * HW;

#pragma unroll
  for (int t = 0; t < 16; ++t) {
    int q = tid + t * 256;
    int r = q >> 5, c4 = (q & 31) << 2;
    *(float4*)&Xs[swz4(r, c4)] = *(const float4*)&Ug[(r << 7) + c4];
  }
  mm_step<true, true, true>(cc, nullptr, Xs, Pan, Ys, tid);
  mm_step<false, true, false>(cc, Ys, nullptr, Pan, Xs, tid);
  __syncthreads();
#pragma unroll
  for (int t = 0; t < 64; ++t) {
    int q = tid + t * 256;
    int r = q >> 7, cx = q & 127;
    int idx = (r << 7) + (((((cx >> 2) ^ ((r >> 3) & 7)) << 2)) | (cx & 3));
    Xs[idx] *= Pp[q];
  }
  mm_step<true, false, true>(cc, nullptr, Xs, Pan, Ys, tid);
  mm_step<false, false, false>(cc, Ys, nullptr, Pan, Xs, tid);
  __syncthreads();
#pragma unroll
  for (int t = 0; t < 16; ++t) {
    int q = tid + t * 256;
    int r = q >> 5, c4 = (q & 31) << 2;
    *(float4*)&Ug[(r << 7) + c4] = *(float4*)&Xs[swz4(r, c4)];
  }
}

// ---------- K5: catmean lower half = mean_b(y1) ----------
__global__ void k5_mean(const float* __restrict__ x1p, float* __restrict__ cmL) {
  int idx = blockIdx.x * 256 + threadIdx.x;
  int c = idx >> 14, s = idx & 16383;
  float sum = 0.f;
#pragma unroll
  for (int b = 0; b < 8; ++b) sum += x1p[(size_t)(b * 96 + c) * HW + s];
  cmL[idx] = sum * 0.125f;
}

// ---------- K6: skfeat = catmean @ lin2_w^T + lin2_b ----------
__global__ __launch_bounds__(256) void k6_skf(
    const float* __restrict__ cm, const float* __restrict__ w2T,
    const float* __restrict__ b2, float* __restrict__ skf) {
  int tid = threadIdx.x;
  int lane = tid & 63;
  int row = (blockIdx.x >> 1) * 64 + lane;    // 512 blocks
  int n0 = __builtin_amdgcn_readfirstlane((blockIdx.x & 1) * 96 + (tid >> 6) * 24);
  float acc[24];
#pragma unroll
  for (int j = 0; j < 24; ++j) acc[j] = b2[n0 + j];
#pragma unroll 4
  for (int k = 0; k < 192; ++k) {
    float a = cm[(size_t)k * HW + row];
    const float* wr = w2T + k * 192 + n0;
#pragma unroll
    for (int j = 0; j < 24; ++j) acc[j] = fmaf(a, wr[j], acc[j]);
  }
#pragma unroll
  for (int j = 0; j < 24; ++j) skf[(size_t)(n0 + j) * HW + row] = acc[j];
}

// ---------- K7: k2 = relu(skf@k2_w^T + k2_b); P2 = exp(-e*k2) ----------
__global__ __launch_bounds__(256) void k7_k2(
    const float* __restrict__ skf, const float* __restrict__ w2T,
    const float* __restrict__ b2, const float* __restrict__ ee,
    float* __restrict__ P2) {
  int tid = threadIdx.x;
  int lane = tid & 63;
  int row = (blockIdx.x >> 1) * 64 + lane;    // 512 blocks
  int n0 = __builtin_amdgcn_readfirstlane((blockIdx.x & 1) * 96 + (tid >> 6) * 24);
  float acc[24];
#pragma unroll
  for (int j = 0; j < 24; ++j) acc[j] = b2[n0 + j];
#pragma unroll 4
  for (int k = 0; k < 192; ++k) {
    float a = skf[(size_t)k * HW + row];
    const float* wr = w2T + k * 192 + n0;
#pragma unroll
    for (int j = 0; j < 24; ++j) acc[j] = fmaf(a, wr[j], acc[j]);
  }
  float er = ee[row];
#pragma unroll
  for (int j = 0; j < 24; ++j)
    P2[(size_t)(n0 + j) * HW + row] = expf(-er * fmaxf(acc[j], 0.f));
}

// ---------- K9: lin3 + LN + silu(z)* + out GEMM, wave-chunked via LDS ----------
__global__ __launch_bounds__(256) void k9_epilogue(
    const float* __restrict__ y1, const float* __restrict__ y2,
    const float* __restrict__ z,
    const float* __restrict__ lin3T, const float* __restrict__ lin3b,
    const float* __restrict__ lng, const float* __restrict__ lnb,
    const float* __restrict__ outT, const float* __restrict__ outb,
    float* __restrict__ out) {
  __shared__ float ts[64 * 97];
  int tid = threadIdx.x;
  int lane = tid & 63;
  int n0 = __builtin_amdgcn_readfirstlane((tid >> 6) * 24);
  int gpos = blockIdx.x * 64 + lane;          // 2048 blocks
  int b = gpos >> 14, hw = gpos & 16383;
  float acc[24];
#pragma unroll
  for (int j = 0; j < 24; ++j) acc[j] = lin3b[n0 + j];
#pragma unroll 4
  for (int k = 0; k < 96; ++k) {
    float a = y1[(size_t)(b * 96 + k) * HW + hw];
    const float* wr = lin3T + k * 96 + n0;
#pragma unroll
    for (int j = 0; j < 24; ++j) acc[j] = fmaf(a, wr[j], acc[j]);
  }
#pragma unroll 4
  for (int k = 0; k < 96; ++k) {
    float a = y2[(size_t)(b * 96 + k) * HW + hw];
    const float* wr = lin3T + (96 + k) * 96 + n0;
#pragma unroll
    for (int j = 0; j < 24; ++j) acc[j] = fmaf(a, wr[j], acc[j]);
  }
#pragma unroll
  for (int j = 0; j < 24; ++j) ts[lane * 97 + n0 + j] = acc[j];
  __syncthreads();
  float mu = 0.f, var = 0.f;
#pragma unroll
  for (int k = 0; k < 96; ++k) mu += ts[lane * 97 + k];
  mu *= (1.f / 96.f);
#pragma unroll
  for (int k = 0; k < 96; ++k) {
    float d = ts[lane * 97 + k] - mu;
    var = fmaf(d, d, var);
  }
  var *= (1.f / 96.f);
  float inv = rsqrtf(var + 1e-5f);
  __syncthreads();
  const float* zp = z + (size_t)gpos * 96 + n0;
#pragma unroll
  for (int j = 0; j < 24; ++j) {
    float zv = zp[j];
    float sil = zv / (1.f + expf(-zv));
    float u = (acc[j] - mu) * inv * lng[n0 + j] + lnb[n0 + j];
    ts[lane * 97 + n0 + j] = u * sil;
  }
  __syncthreads();
  float acc2[24];
#pragma unroll
  for (int j = 0; j < 24; ++j) acc2[j] = outb[n0 + j];
#pragma unroll 4
  for (int k = 0; k < 96; ++k) {
    float u = ts[lane * 97 + k];
    const float* wr = outT + k * 96 + n0;
#pragma unroll
    for (int j = 0; j < 24; ++j) acc2[j] = fmaf(u, wr[j], acc2[j]);
  }
#pragma unroll
  for (int j = 0; j < 24; ++j)
    out[(size_t)(b * 96 + n0 + j) * HW + hw] = acc2[j];
}

extern "C" void kernel_launch(void* const* d_in, const int* in_sizes, int n_in,
                              void* d_out, int out_size, void* d_ws, size_t ws_size,
                              hipStream_t stream) {
  const float* x      = (const float*)d_in[0];
  const float* fe     = (const float*)d_in[1];
  const float* of     = (const float*)d_in[2];
  const float* dw_w   = (const float*)d_in[3];
  const float* dw_b   = (const float*)d_in[4];
  const float* lin_w  = (const float*)d_in[5];
  const float* lin_b  = (const float*)d_in[6];
  const float* k_w    = (const float*)d_in[7];
  const float* k_b    = (const float*)d_in[8];
  const float* lin2_w = (const float*)d_in[9];
  const float* lin2_b = (const float*)d_in[10];
  const float* k2_w   = (const float*)d_in[11];
  const float* k2_b   = (const float*)d_in[12];
  const float* lin3_w = (const float*)d_in[13];
  const float* lin3_b = (const float*)d_in[14];
  const float* ln_g   = (const float*)d_in[15];
  const float* ln_b   = (const float*)d_in[16];
  const float* out_w  = (const float*)d_in[17];
  const float* out_b  = (const float*)d_in[18];
  float* out = (float*)d_out;

  float* ws    = (float*)d_ws;
  float* x1p   = ws;                      // [B][96][HW]  (x1 -> y1 -> y2 low)
  float* z     = x1p   + 12582912;        // [B][HW][96]
  float* ofp   = z     + 12582912;        // [B][96][HW]  (xc first, then outline planes)
  float* cm    = ofp   + 12582912;        // [192][HW]
  float* skf   = cm    + 3145728;         // [192][HW]
  float* P1    = skf   + 3145728;         // [96][HW]
  float* P2    = P1    + 1572864;         // [192][HW]
  float* cc    = P2    + 3145728;         // [128][128]
  float* ee    = cc    + 16384;           // [128][128]
  float* linT  = ee    + 16384;           // [96][192]
  float* kT    = linT  + 18432;           // [96][96]
  float* lin2T = kT    + 9216;            // [192][192]
  float* k2T   = lin2T + 36864;           // [192][192]
  float* lin3T = k2T   + 36864;           // [192][96]
  float* outT  = lin3T + 18432;           // [96][96]
  float* fet   = outT  + 9216;            // [96][HW] = 1572864
  float* xc    = ofp;                     // aliases ofp: dead after klin, before k3
  (void)in_sizes; (void)n_in; (void)out_size; (void)ws_size;

  k0_tables<<<64, 256, 0, stream>>>(cc, ee);
  k_wt<<<72, 256, 0, stream>>>(lin_w, linT, 192, 96);
  k_wt<<<36, 256, 0, stream>>>(k_w, kT, 96, 96);
  k_wt<<<144, 256, 0, stream>>>(lin2_w, lin2T, 192, 192);
  k_wt<<<144, 256, 0, stream>>>(k2_w, k2T, 192, 192);
  k_wt<<<72, 256, 0, stream>>>(lin3_w, lin3T, 96, 192);
  k_wt<<<36, 256, 0, stream>>>(out_w, outT, 96, 96);
  k_tfe<<<256, 256, 0, stream>>>(fe, fet);

  kconv<<<12288, 256, 0, stream>>>(x, dw_w, dw_b, xc);
  klin<<<2048, 256, 0, stream>>>(xc, linT, lin_b, x1p, z);
  k3_transpose_mean<<<256, 256, 0, stream>>>(of, ofp, cm + (size_t)96 * HW);
  k3b_kgemm<<<256, 256, 0, stream>>>(fet, cm + (size_t)96 * HW, kT, k_b, ee, P1);
  heat_kernel<<<768, 256, 0, stream>>>(x1p, x1p, P1, cc, 96);
  k5_mean<<<6144, 256, 0, stream>>>(x1p, cm);
  k6_skf<<<512, 256, 0, stream>>>(cm, lin2T, lin2_b, skf);
  k7_k2<<<512, 256, 0, stream>>>(skf, k2T, k2_b, ee, P2);
  heat_kernel<<<1536, 256, 0, stream>>>(x1p, ofp, P2, cc, 192);
  k9_epilogue<<<2048, 256, 0, stream>>>(x1p, ofp, z, lin3T, lin3_b, ln_g, ln_b,
                                        outT, out_b, out);
}

// Round 6
// 508.594 us; speedup vs baseline: 4.4742x; 2.0627x over previous
//
#include <hip/hip_runtime.h>
#include <math.h>
#include <stdint.h>

#ifndef M_PI
#define M_PI 3.14159265358979323846
#endif

#define HW 16384

typedef __attribute__((ext_vector_type(8))) short s8bf;    // 8 bf16 = 4 VGPR
typedef __attribute__((ext_vector_type(4))) float f32x4;   // MFMA C/D

union FragU { uint32_t u[4]; s8bf s; };

// ---------- bf16 split helpers ----------
__device__ __forceinline__ uint32_t bf16h(float x) {
  uint32_t u = __float_as_uint(x);
  return (u + 0x7FFFu + ((u >> 16) & 1u)) >> 16;     // RNE, low 16 bits
}
__device__ __forceinline__ uint32_t packhl(float x) {  // u32 = (hi<<16)|lo
  uint32_t h = bf16h(x);
  float r = x - __uint_as_float(h << 16);
  return (h << 16) | bf16h(r);
}
__device__ __forceinline__ void unpack8(const uint32_t* w, s8bf& hi, s8bf& lo) {
  FragU H, L;
#pragma unroll
  for (int j = 0; j < 4; ++j) {
    H.u[j] = __builtin_amdgcn_perm(w[2 * j + 1], w[2 * j], 0x07060302u);
    L.u[j] = __builtin_amdgcn_perm(w[2 * j + 1], w[2 * j], 0x05040100u);
  }
  hi = H.s; lo = L.s;
}

// ---------- tables: decay exponent (cc kept for layout compat, unused) ----------
__global__ void k0_tables(float* __restrict__ cc, float* __restrict__ ee) {
  int gid = blockIdx.x * 256 + threadIdx.x;   // 16384
  int n = gid >> 7, m = gid & 127;
  double v = cos((double)n * ((double)m + 0.5) * (M_PI / 128.0)) * sqrt(2.0 / 128.0);
  if (n == 0) v *= 0.70710678118654752440;
  cc[gid] = (float)v;
  double wn = (double)n * (M_PI / 128.0), wm = (double)m * (M_PI / 128.0);
  ee[gid] = (float)(wn * wn + wm * wm);
}

// ---------- DCT matrix fragment constants (A-operand order, hi/lo split) ----------
__device__ __forceinline__ float cval(int a, int b) {
  double v = cos((double)a * ((double)b + 0.5) * (M_PI / 128.0)) * sqrt(2.0 / 128.0);
  if (a == 0) v *= 0.70710678118654752440;
  return (float)v;
}
// FA = frags of C (A-form; also B-form of C^T). FT = frags of C^T (also B-form of C).
// index: ((mt*4+ks)*64+lane)*4 + j ; elem e=2j -> low16, e=2j+1 -> high16.
__global__ void k0_frags(uint32_t* __restrict__ FAh, uint32_t* __restrict__ FAl,
                         uint32_t* __restrict__ FTh, uint32_t* __restrict__ FTl) {
  int tid = blockIdx.x * 256 + threadIdx.x;   // 2048
  int lane = tid & 63, fid = tid >> 6;
  int mt = fid >> 2, ks = fid & 3;
  int n = 16 * mt + (lane & 15);
  int k0 = 32 * ks + 8 * (lane >> 4);
#pragma unroll
  for (int j = 0; j < 4; ++j) {
    float a0 = cval(n, k0 + 2 * j), a1 = cval(n, k0 + 2 * j + 1);
    uint32_t p0 = packhl(a0), p1 = packhl(a1);
    FAh[tid * 4 + j] = (p0 >> 16) | (p1 & 0xFFFF0000u);
    FAl[tid * 4 + j] = (p0 & 0xFFFFu) | (p1 << 16);
    float b0 = cval(k0 + 2 * j, n), b1 = cval(k0 + 2 * j + 1, n);
    uint32_t q0 = packhl(b0), q1 = packhl(b1);
    FTh[tid * 4 + j] = (q0 >> 16) | (q1 & 0xFFFF0000u);
    FTl[tid * 4 + j] = (q0 & 0xFFFFu) | (q1 << 16);
  }
}

// ---------- generic weight transpose: src[D][C] -> dst[C][D] ----------
__global__ void k_wt(const float* __restrict__ src, float* __restrict__ dst, int D, int C) {
  int gid = blockIdx.x * 256 + threadIdx.x;
  if (gid >= D * C) return;
  int d = gid / C, c = gid % C;
  dst[c * D + d] = src[gid];
}

// ---------- fe transpose: [HW][96] -> [96][HW] ----------
__global__ __launch_bounds__(256) void k_tfe(const float* __restrict__ fe,
                                             float* __restrict__ fet) {
  __shared__ float tile[64 * 97];
  int hw0 = blockIdx.x * 64;
  int tid = threadIdx.x;
#pragma unroll
  for (int t = 0; t < 24; ++t) {
    int l = tid + t * 256;
    int r = l / 96, c0 = l % 96;
    tile[r * 97 + c0] = fe[((size_t)hw0 + r) * 96 + c0];
  }
  __syncthreads();
#pragma unroll
  for (int t = 0; t < 24; ++t) {
    int l = tid + t * 256;
    int c0 = l >> 6, r = l & 63;
    fet[(size_t)c0 * HW + hw0 + r] = tile[r * 97 + c0];
  }
}

// ---------- KC: depthwise 3x3 conv, float4 per thread, plane-major out ----------
__global__ __launch_bounds__(256) void kconv(
    const float* __restrict__ x, const float* __restrict__ dw_w,
    const float* __restrict__ dw_b, float* __restrict__ xc) {
  int gid = blockIdx.x * 256 + threadIdx.x;   // B*96*4096 = 3145728
  int p = gid >> 12;                          // plane b*96+c
  int q = gid & 4095;
  int h = q >> 5, w4 = (q & 31) << 2;
  int c = p % 96;
  const float* pw = dw_w + c * 9;
  const float* row = x + (size_t)p * HW + h * 128 + w4;
  bool tp = h > 0, bt = h < 127, lf = w4 > 0, rt = w4 < 124;
  float4 t_, m_, b_;
  float tl, tr, ml, mr, bl, br;
  m_ = *(const float4*)row;
  ml = lf ? row[-1] : 0.f;
  mr = rt ? row[4] : 0.f;
  if (tp) {
    t_ = *(const float4*)(row - 128);
    tl = lf ? row[-129] : 0.f;
    tr = rt ? row[-124] : 0.f;
  } else { t_ = make_float4(0.f, 0.f, 0.f, 0.f); tl = tr = 0.f; }
  if (bt) {
    b_ = *(const float4*)(row + 128);
    bl = lf ? row[127] : 0.f;
    br = rt ? row[132] : 0.f;
  } else { b_ = make_float4(0.f, 0.f, 0.f, 0.f); bl = br = 0.f; }
  float w0 = pw[0], w1 = pw[1], w2 = pw[2], w3 = pw[3], w4w = pw[4],
        w5 = pw[5], w6 = pw[6], w7 = pw[7], w8 = pw[8];
  float bias = dw_b[c];
  float4 o;
  o.x = tl * w0 + t_.x * w1 + t_.y * w2 + ml * w3 + m_.x * w4w + m_.y * w5 + bl * w6 + b_.x * w7 + b_.y * w8 + bias;
  o.y = t_.x * w0 + t_.y * w1 + t_.z * w2 + m_.x * w3 + m_.y * w4w + m_.z * w5 + b_.x * w6 + b_.y * w7 + b_.z * w8 + bias;
  o.z = t_.y * w0 + t_.z * w1 + t_.w * w2 + m_.y * w3 + m_.z * w4w + m_.w * w5 + b_.y * w6 + b_.z * w7 + b_.w * w8 + bias;
  o.w = t_.z * w0 + t_.w * w1 + tr * w2 + m_.z * w3 + m_.w * w4w + mr * w5 + b_.z * w6 + b_.w * w7 + br * w8 + bias;
  *(float4*)(xc + (size_t)p * HW + h * 128 + w4) = o;
}

// ---------- KL: lin GEMM  [B*HW,96] @ [96,192]; wave owns 48-wide N-chunk ----------
__global__ __launch_bounds__(256) void klin(
    const float* __restrict__ xc, const float* __restrict__ linT,
    const float* __restrict__ lin_b, float* __restrict__ x1p, float* __restrict__ z) {
  int tid = threadIdx.x;
  int lane = tid & 63;
  int n0 = __builtin_amdgcn_readfirstlane((tid >> 6) * 48);
  int gpos = blockIdx.x * 64 + lane;          // 2048 blocks
  int b = gpos >> 14, hw = gpos & 16383;
  float acc[48];
#pragma unroll
  for (int j = 0; j < 48; ++j) acc[j] = lin_b[n0 + j];
#pragma unroll 4
  for (int c = 0; c < 96; ++c) {
    float a = xc[(size_t)(b * 96 + c) * HW + hw];
    const float* wr = linT + c * 192 + n0;
#pragma unroll
    for (int j = 0; j < 48; ++j) acc[j] = fmaf(a, wr[j], acc[j]);
  }
  if (n0 < 96) {
#pragma unroll
    for (int j = 0; j < 48; ++j)
      x1p[(size_t)(b * 96 + n0 + j) * HW + hw] = acc[j];
  } else {
    float* zp = z + (size_t)gpos * 96 + (n0 - 96);
#pragma unroll
    for (int j = 0; j < 48; j += 4)
      *(float4*)&zp[j] = make_float4(acc[j], acc[j + 1], acc[j + 2], acc[j + 3]);
  }
}

// ---------- K3: outline_feat transpose to plane-major + mean over B ----------
__global__ __launch_bounds__(256) void k3_transpose_mean(
    const float* __restrict__ of, float* __restrict__ ofp, float* __restrict__ cmU) {
  __shared__ float tile[64 * 97];
  int hw0 = blockIdx.x * 64;
  int tid = threadIdx.x;
  float sum[24];
#pragma unroll
  for (int t = 0; t < 24; ++t) sum[t] = 0.f;
  for (int b = 0; b < 8; ++b) {
    __syncthreads();
#pragma unroll
    for (int t = 0; t < 24; ++t) {
      int l = tid + t * 256;
      int r = l / 96, c0 = l % 96;
      tile[r * 97 + c0] = of[((size_t)b * 16384 + hw0 + r) * 96 + c0];
    }
    __syncthreads();
#pragma unroll
    for (int t = 0; t < 24; ++t) {
      int l = tid + t * 256;
      int c0 = l >> 6, r = l & 63;
      float v = tile[r * 97 + c0];
      sum[t] += v;
      ofp[(size_t)(b * 96 + c0) * HW + hw0 + r] = v;
    }
  }
#pragma unroll
  for (int t = 0; t < 24; ++t) {
    int l = tid + t * 256;
    int c0 = l >> 6, r = l & 63;
    cmU[(size_t)c0 * HW + hw0 + r] = sum[t] * 0.125f;
  }
}

// ---------- K3b: k = relu((fet+otm)@k_w^T + k_b); P1 = exp(-e*k) ----------
__global__ __launch_bounds__(256) void k3b_kgemm(
    const float* __restrict__ fet, const float* __restrict__ otm,
    const float* __restrict__ kT, const float* __restrict__ kb,
    const float* __restrict__ ee, float* __restrict__ P1) {
  int tid = threadIdx.x;
  int lane = tid & 63;
  int n0 = __builtin_amdgcn_readfirstlane((tid >> 6) * 24);
  int row = blockIdx.x * 64 + lane;           // 256 blocks
  float acc[24];
#pragma unroll
  for (int j = 0; j < 24; ++j) acc[j] = kb[n0 + j];
#pragma unroll 4
  for (int c = 0; c < 96; ++c) {
    float a = fet[(size_t)c * HW + row] + otm[(size_t)c * HW + row];
    const float* wr = kT + c * 96 + n0;
#pragma unroll
    for (int j = 0; j < 24; ++j) acc[j] = fmaf(a, wr[j], acc[j]);
  }
  float er = ee[row];
#pragma unroll
  for (int j = 0; j < 24; ++j)
    P1[(size_t)(n0 + j) * HW + row] = expf(-er * fmaxf(acc[j], 0.f));
}

// ---------- MFMA heat pass ----------
// One 16x16x32 step of the 2x2-wave, 4x4-tile plan. DATA_A: data matrix is the
// A-operand (row-major LDS, packed u32); else data is B (col-major LDS).
template <bool DATA_A>
__device__ __forceinline__ void heat_step(
    const uint32_t* __restrict__ Fh, const uint32_t* __restrict__ Fl,
    const uint32_t* __restrict__ Ds, f32x4 (&acc)[4][4], int wm, int wn, int lane) {
  const int l15 = lane & 15, lg = lane >> 4;
  const int wd = DATA_A ? wm : wn;   // data tile group (rows if A, cols if B)
  const int wf = DATA_A ? wn : wm;   // C-frag tile group
#pragma unroll
  for (int ksl = 0; ksl < 4; ++ksl) {
    s8bf Dhi[4], Dlo[4], Fhi[4], Flo[4];
#pragma unroll
    for (int t = 0; t < 4; ++t) {   // data frags from LDS (4x ds_read_b64 each)
      const uint32_t* p = Ds + (64 * wd + 16 * t + l15) * 130 + 32 * ksl + 8 * lg;
      uint32_t wv[8];
      *(uint2*)&wv[0] = *(const uint2*)(p);
      *(uint2*)&wv[2] = *(const uint2*)(p + 2);
      *(uint2*)&wv[4] = *(const uint2*)(p + 4);
      *(uint2*)&wv[6] = *(const uint2*)(p + 6);
      unpack8(wv, Dhi[t], Dlo[t]);
    }
#pragma unroll
    for (int t = 0; t < 4; ++t) {   // C frags from global (L2), pre-split
      int base = (((4 * wf + t) * 4 + ksl) * 64 + lane) * 4;
      FragU H, L;
      *(uint4*)H.u = *(const uint4*)(Fh + base);
      *(uint4*)L.u = *(const uint4*)(Fl + base);
      Fhi[t] = H.s; Flo[t] = L.s;
    }
    const s8bf* Ah = DATA_A ? Dhi : Fhi;
    const s8bf* Al = DATA_A ? Dlo : Flo;
    const s8bf* Bh = DATA_A ? Fhi : Dhi;
    const s8bf* Bl = DATA_A ? Flo : Dlo;
#pragma unroll
    for (int mi = 0; mi < 4; ++mi)
#pragma unroll
      for (int ni = 0; ni < 4; ++ni)
        acc[mi][ni] = __builtin_amdgcn_mfma_f32_16x16x32_bf16(Ah[mi], Bh[ni], acc[mi][ni], 0, 0, 0);
#pragma unroll
    for (int mi = 0; mi < 4; ++mi)
#pragma unroll
      for (int ni = 0; ni < 4; ++ni)
        acc[mi][ni] = __builtin_amdgcn_mfma_f32_16x16x32_bf16(Ah[mi], Bl[ni], acc[mi][ni], 0, 0, 0);
#pragma unroll
    for (int mi = 0; mi < 4; ++mi)
#pragma unroll
      for (int ni = 0; ni < 4; ++ni)
        acc[mi][ni] = __builtin_amdgcn_mfma_f32_16x16x32_bf16(Al[mi], Bh[ni], acc[mi][ni], 0, 0, 0);
  }
}

__global__ __launch_bounds__(256, 2) void heat_mfma(
    float* bufA, float* bufB, const float* __restrict__ P,
    const uint32_t* __restrict__ FAh, const uint32_t* __restrict__ FAl,
    const uint32_t* __restrict__ FTh, const uint32_t* __restrict__ FTl, int Ceff) {
  __shared__ uint32_t Ds[128 * 130];   // 66560 B -> 2 blocks/CU
  const int tid = threadIdx.x;
  const int lane = tid & 63;
  const int w = tid >> 6;
  const int wm = w >> 1, wn = w & 1;
  const int plane = blockIdx.x;
  const int b = plane / Ceff, c = plane % Ceff;
  float* Ug = (c < 96) ? (bufA + (size_t)(b * 96 + c) * HW)
                       : (bufB + (size_t)(b * 96 + (c - 96)) * HW);
  const float* Pp = P + (size_t)c * HW;

  // ---- stage U -> Ds col-major packed: Ds[col*130 + row] ----
  {
    int col = tid & 127, r0 = tid >> 7;
#pragma unroll
    for (int i = 0; i < 64; ++i) {
      int row = r0 + 2 * i;
      Ds[col * 130 + row] = packhl(Ug[row * 128 + col]);
    }
  }
  __syncthreads();

  f32x4 acc[4][4];
  const f32x4 zero4 = {0.f, 0.f, 0.f, 0.f};

  // ---- step1: T = C * U   (A = C frags, B = U col-major) ----
#pragma unroll
  for (int mi = 0; mi < 4; ++mi)
#pragma unroll
    for (int ni = 0; ni < 4; ++ni) acc[mi][ni] = zero4;
  heat_step<false>(FAh, FAl, Ds, acc, wm, wn, lane);
  __syncthreads();
#pragma unroll
  for (int mi = 0; mi < 4; ++mi)
#pragma unroll
    for (int ni = 0; ni < 4; ++ni)
#pragma unroll
      for (int r = 0; r < 4; ++r)
        Ds[(64 * wm + 16 * mi + 4 * (lane >> 4) + r) * 130 + 64 * wn + 16 * ni + (lane & 15)] =
            packhl(acc[mi][ni][r]);
  __syncthreads();

  // ---- step2: S = T * C^T  (A = T row-major, B = FA), then S *= P ----
#pragma unroll
  for (int mi = 0; mi < 4; ++mi)
#pragma unroll
    for (int ni = 0; ni < 4; ++ni) acc[mi][ni] = zero4;
  heat_step<true>(FAh, FAl, Ds, acc, wm, wn, lane);
#pragma unroll
  for (int mi = 0; mi < 4; ++mi)
#pragma unroll
    for (int ni = 0; ni < 4; ++ni) {
      int row = 64 * wm + 16 * mi + 4 * (lane >> 4);
      int col = 64 * wn + 16 * ni + (lane & 15);
#pragma unroll
      for (int r = 0; r < 4; ++r)
        acc[mi][ni][r] *= Pp[(row + r) * 128 + col];
    }
  __syncthreads();
#pragma unroll
  for (int mi = 0; mi < 4; ++mi)
#pragma unroll
    for (int ni = 0; ni < 4; ++ni)
#pragma unroll
      for (int r = 0; r < 4; ++r)
        Ds[(64 * wn + 16 * ni + (lane & 15)) * 130 + 64 * wm + 16 * mi + 4 * (lane >> 4) + r] =
            packhl(acc[mi][ni][r]);
  __syncthreads();

  // ---- step3: T2 = C^T * S  (A = FT, B = S col-major) ----
#pragma unroll
  for (int mi = 0; mi < 4; ++mi)
#pragma unroll
    for (int ni = 0; ni < 4; ++ni) acc[mi][ni] = zero4;
  heat_step<false>(FTh, FTl, Ds, acc, wm, wn, lane);
  __syncthreads();
#pragma unroll
  for (int mi = 0; mi < 4; ++mi)
#pragma unroll
    for (int ni = 0; ni < 4; ++ni)
#pragma unroll
      for (int r = 0; r < 4; ++r)
        Ds[(64 * wm + 16 * mi + 4 * (lane >> 4) + r) * 130 + 64 * wn + 16 * ni + (lane & 15)] =
            packhl(acc[mi][ni][r]);
  __syncthreads();

  // ---- step4: Y = T2 * C  (A = T2 row-major, B = FT) -> global ----
#pragma unroll
  for (int mi = 0; mi < 4; ++mi)
#pragma unroll
    for (int ni = 0; ni < 4; ++ni) acc[mi][ni] = zero4;
  heat_step<true>(FTh, FTl, Ds, acc, wm, wn, lane);
#pragma unroll
  for (int mi = 0; mi < 4; ++mi)
#pragma unroll
    for (int ni = 0; ni < 4; ++ni) {
      int row = 64 * wm + 16 * mi + 4 * (lane >> 4);
      int col = 64 * wn + 16 * ni + (lane & 15);
#pragma unroll
      for (int r = 0; r < 4; ++r)
        Ug[(row + r) * 128 + col] = acc[mi][ni][r];
    }
}

// ---------- K5: catmean lower half = mean_b(y1) ----------
__global__ void k5_mean(const float* __restrict__ x1p, float* __restrict__ cmL) {
  int idx = blockIdx.x * 256 + threadIdx.x;
  int c = idx >> 14, s = idx & 16383;
  float sum = 0.f;
#pragma unroll
  for (int b = 0; b < 8; ++b) sum += x1p[(size_t)(b * 96 + c) * HW + s];
  cmL[idx] = sum * 0.125f;
}

// ---------- K6: skfeat = catmean @ lin2_w^T + lin2_b ----------
__global__ __launch_bounds__(256) void k6_skf(
    const float* __restrict__ cm, const float* __restrict__ w2T,
    const float* __restrict__ b2, float* __restrict__ skf) {
  int tid = threadIdx.x;
  int lane = tid & 63;
  int row = (blockIdx.x >> 1) * 64 + lane;    // 512 blocks
  int n0 = __builtin_amdgcn_readfirstlane((blockIdx.x & 1) * 96 + (tid >> 6) * 24);
  float acc[24];
#pragma unroll
  for (int j = 0; j < 24; ++j) acc[j] = b2[n0 + j];
#pragma unroll 4
  for (int k = 0; k < 192; ++k) {
    float a = cm[(size_t)k * HW + row];
    const float* wr = w2T + k * 192 + n0;
#pragma unroll
    for (int j = 0; j < 24; ++j) acc[j] = fmaf(a, wr[j], acc[j]);
  }
#pragma unroll
  for (int j = 0; j < 24; ++j) skf[(size_t)(n0 + j) * HW + row] = acc[j];
}

// ---------- K7: k2 = relu(skf@k2_w^T + k2_b); P2 = exp(-e*k2) ----------
__global__ __launch_bounds__(256) void k7_k2(
    const float* __restrict__ skf, const float* __restrict__ w2T,
    const float* __restrict__ b2, const float* __restrict__ ee,
    float* __restrict__ P2) {
  int tid = threadIdx.x;
  int lane = tid & 63;
  int row = (blockIdx.x >> 1) * 64 + lane;    // 512 blocks
  int n0 = __builtin_amdgcn_readfirstlane((blockIdx.x & 1) * 96 + (tid >> 6) * 24);
  float acc[24];
#pragma unroll
  for (int j = 0; j < 24; ++j) acc[j] = b2[n0 + j];
#pragma unroll 4
  for (int k = 0; k < 192; ++k) {
    float a = skf[(size_t)k * HW + row];
    const float* wr = w2T + k * 192 + n0;
#pragma unroll
    for (int j = 0; j < 24; ++j) acc[j] = fmaf(a, wr[j], acc[j]);
  }
  float er = ee[row];
#pragma unroll
  for (int j = 0; j < 24; ++j)
    P2[(size_t)(n0 + j) * HW + row] = expf(-er * fmaxf(acc[j], 0.f));
}

// ---------- K9: lin3 + LN + silu(z)* + out GEMM, wave-chunked via LDS ----------
__global__ __launch_bounds__(256) void k9_epilogue(
    const float* __restrict__ y1, const float* __restrict__ y2,
    const float* __restrict__ z,
    const float* __restrict__ lin3T, const float* __restrict__ lin3b,
    const float* __restrict__ lng, const float* __restrict__ lnb,
    const float* __restrict__ outT, const float* __restrict__ outb,
    float* __restrict__ out) {
  __shared__ float ts[64 * 97];
  int tid = threadIdx.x;
  int lane = tid & 63;
  int n0 = __builtin_amdgcn_readfirstlane((tid >> 6) * 24);
  int gpos = blockIdx.x * 64 + lane;          // 2048 blocks
  int b = gpos >> 14, hw = gpos & 16383;
  float acc[24];
#pragma unroll
  for (int j = 0; j < 24; ++j) acc[j] = lin3b[n0 + j];
#pragma unroll 4
  for (int k = 0; k < 96; ++k) {
    float a = y1[(size_t)(b * 96 + k) * HW + hw];
    const float* wr = lin3T + k * 96 + n0;
#pragma unroll
    for (int j = 0; j < 24; ++j) acc[j] = fmaf(a, wr[j], acc[j]);
  }
#pragma unroll 4
  for (int k = 0; k < 96; ++k) {
    float a = y2[(size_t)(b * 96 + k) * HW + hw];
    const float* wr = lin3T + (96 + k) * 96 + n0;
#pragma unroll
    for (int j = 0; j < 24; ++j) acc[j] = fmaf(a, wr[j], acc[j]);
  }
#pragma unroll
  for (int j = 0; j < 24; ++j) ts[lane * 97 + n0 + j] = acc[j];
  __syncthreads();
  float mu = 0.f, var = 0.f;
#pragma unroll
  for (int k = 0; k < 96; ++k) mu += ts[lane * 97 + k];
  mu *= (1.f / 96.f);
#pragma unroll
  for (int k = 0; k < 96; ++k) {
    float d = ts[lane * 97 + k] - mu;
    var = fmaf(d, d, var);
  }
  var *= (1.f / 96.f);
  float inv = rsqrtf(var + 1e-5f);
  __syncthreads();
  const float* zp = z + (size_t)gpos * 96 + n0;
#pragma unroll
  for (int j = 0; j < 24; ++j) {
    float zv = zp[j];
    float sil = zv / (1.f + expf(-zv));
    float u = (acc[j] - mu) * inv * lng[n0 + j] + lnb[n0 + j];
    ts[lane * 97 + n0 + j] = u * sil;
  }
  __syncthreads();
  float acc2[24];
#pragma unroll
  for (int j = 0; j < 24; ++j) acc2[j] = outb[n0 + j];
#pragma unroll 4
  for (int k = 0; k < 96; ++k) {
    float u = ts[lane * 97 + k];
    const float* wr = outT + k * 96 + n0;
#pragma unroll
    for (int j = 0; j < 24; ++j) acc2[j] = fmaf(u, wr[j], acc2[j]);
  }
#pragma unroll
  for (int j = 0; j < 24; ++j)
    out[(size_t)(b * 96 + n0 + j) * HW + hw] = acc2[j];
}

extern "C" void kernel_launch(void* const* d_in, const int* in_sizes, int n_in,
                              void* d_out, int out_size, void* d_ws, size_t ws_size,
                              hipStream_t stream) {
  const float* x      = (const float*)d_in[0];
  const float* fe     = (const float*)d_in[1];
  const float* of     = (const float*)d_in[2];
  const float* dw_w   = (const float*)d_in[3];
  const float* dw_b   = (const float*)d_in[4];
  const float* lin_w  = (const float*)d_in[5];
  const float* lin_b  = (const float*)d_in[6];
  const float* k_w    = (const float*)d_in[7];
  const float* k_b    = (const float*)d_in[8];
  const float* lin2_w = (const float*)d_in[9];
  const float* lin2_b = (const float*)d_in[10];
  const float* k2_w   = (const float*)d_in[11];
  const float* k2_b   = (const float*)d_in[12];
  const float* lin3_w = (const float*)d_in[13];
  const float* lin3_b = (const float*)d_in[14];
  const float* ln_g   = (const float*)d_in[15];
  const float* ln_b   = (const float*)d_in[16];
  const float* out_w  = (const float*)d_in[17];
  const float* out_b  = (const float*)d_in[18];
  float* out = (float*)d_out;

  float* ws    = (float*)d_ws;
  float* x1p   = ws;                      // [B][96][HW]  (x1 -> y1 -> y2 low)
  float* z     = x1p   + 12582912;        // [B][HW][96]
  float* ofp   = z     + 12582912;        // [B][96][HW]  (xc first, then outline planes)
  float* cm    = ofp   + 12582912;        // [192][HW]
  float* skf   = cm    + 3145728;         // [192][HW]
  float* P1    = skf   + 3145728;         // [96][HW]
  float* P2    = P1    + 1572864;         // [192][HW]
  float* cc    = P2    + 3145728;         // [128][128] (unused by heat now)
  float* ee    = cc    + 16384;           // [128][128]
  float* linT  = ee    + 16384;           // [96][192]
  float* kT    = linT  + 18432;           // [96][96]
  float* lin2T = kT    + 9216;            // [192][192]
  float* k2T   = lin2T + 36864;           // [192][192]
  float* lin3T = k2T   + 36864;           // [192][96]
  float* outT  = lin3T + 18432;           // [96][96]
  float* fet   = outT  + 9216;            // [96][HW] = 1572864
  uint32_t* FAh = (uint32_t*)(fet + 1572864);  // 8192 u32 each
  uint32_t* FAl = FAh + 8192;
  uint32_t* FTh = FAl + 8192;
  uint32_t* FTl = FTh + 8192;
  float* xc    = ofp;                     // aliases ofp: dead after klin, before k3
  (void)in_sizes; (void)n_in; (void)out_size; (void)ws_size;

  k0_tables<<<64, 256, 0, stream>>>(cc, ee);
  k0_frags<<<8, 256, 0, stream>>>(FAh, FAl, FTh, FTl);
  k_wt<<<72, 256, 0, stream>>>(lin_w, linT, 192, 96);
  k_wt<<<36, 256, 0, stream>>>(k_w, kT, 96, 96);
  k_wt<<<144, 256, 0, stream>>>(lin2_w, lin2T, 192, 192);
  k_wt<<<144, 256, 0, stream>>>(k2_w, k2T, 192, 192);
  k_wt<<<72, 256, 0, stream>>>(lin3_w, lin3T, 96, 192);
  k_wt<<<36, 256, 0, stream>>>(out_w, outT, 96, 96);
  k_tfe<<<256, 256, 0, stream>>>(fe, fet);

  kconv<<<12288, 256, 0, stream>>>(x, dw_w, dw_b, xc);
  klin<<<2048, 256, 0, stream>>>(xc, linT, lin_b, x1p, z);
  k3_transpose_mean<<<256, 256, 0, stream>>>(of, ofp, cm + (size_t)96 * HW);
  k3b_kgemm<<<256, 256, 0, stream>>>(fet, cm + (size_t)96 * HW, kT, k_b, ee, P1);
  heat_mfma<<<768, 256, 0, stream>>>(x1p, x1p, P1, FAh, FAl, FTh, FTl, 96);
  k5_mean<<<6144, 256, 0, stream>>>(x1p, cm);
  k6_skf<<<512, 256, 0, stream>>>(cm, lin2T, lin2_b, skf);
  k7_k2<<<512, 256, 0, stream>>>(skf, k2T, k2_b, ee, P2);
  heat_mfma<<<1536, 256, 0, stream>>>(x1p, ofp, P2, FAh, FAl, FTh, FTl, 192);
  k9_epilogue<<<2048, 256, 0, stream>>>(x1p, ofp, z, lin3T, lin3_b, ln_g, ln_b,
                                        outT, out_b, out);
}

// Round 7
// 438.249 us; speedup vs baseline: 5.1924x; 1.1605x over previous
//
#include <hip/hip_runtime.h>
#include <math.h>
#include <stdint.h>

#ifndef M_PI
#define M_PI 3.14159265358979323846
#endif

#define HW 16384
#define BHW 131072

typedef __attribute__((ext_vector_type(8))) short s8bf;    // 8 bf16 = 4 VGPR
typedef __attribute__((ext_vector_type(4))) float f32x4;   // MFMA C/D

union FragU { uint32_t u[4]; s8bf s; };

// ---------- bf16 split helpers ----------
__device__ __forceinline__ uint32_t bf16h(float x) {
  uint32_t u = __float_as_uint(x);
  return (u + 0x7FFFu + ((u >> 16) & 1u)) >> 16;     // RNE, low 16 bits
}
__device__ __forceinline__ uint32_t packhl(float x) {  // u32 = (hi<<16)|lo
  uint32_t h = bf16h(x);
  float r = x - __uint_as_float(h << 16);
  return (h << 16) | bf16h(r);
}
__device__ __forceinline__ void unpack8(const uint32_t* w, s8bf& hi, s8bf& lo) {
  FragU H, L;
#pragma unroll
  for (int j = 0; j < 4; ++j) {
    H.u[j] = __builtin_amdgcn_perm(w[2 * j + 1], w[2 * j], 0x07060302u);
    L.u[j] = __builtin_amdgcn_perm(w[2 * j + 1], w[2 * j], 0x05040100u);
  }
  hi = H.s; lo = L.s;
}

// ---------- tables ----------
__global__ void k0_tables(float* __restrict__ cc, float* __restrict__ ee) {
  int gid = blockIdx.x * 256 + threadIdx.x;   // 16384
  int n = gid >> 7, m = gid & 127;
  double v = cos((double)n * ((double)m + 0.5) * (M_PI / 128.0)) * sqrt(2.0 / 128.0);
  if (n == 0) v *= 0.70710678118654752440;
  cc[gid] = (float)v;
  double wn = (double)n * (M_PI / 128.0), wm = (double)m * (M_PI / 128.0);
  ee[gid] = (float)(wn * wn + wm * wm);
}

// ---------- DCT matrix fragment constants (A-operand order, hi/lo split) ----------
__device__ __forceinline__ float cval(int a, int b) {
  double v = cos((double)a * ((double)b + 0.5) * (M_PI / 128.0)) * sqrt(2.0 / 128.0);
  if (a == 0) v *= 0.70710678118654752440;
  return (float)v;
}
__global__ void k0_frags(uint32_t* __restrict__ FAh, uint32_t* __restrict__ FAl,
                         uint32_t* __restrict__ FTh, uint32_t* __restrict__ FTl) {
  int tid = blockIdx.x * 256 + threadIdx.x;   // 2048
  int lane = tid & 63, fid = tid >> 6;
  int mt = fid >> 2, ks = fid & 3;
  int n = 16 * mt + (lane & 15);
  int k0 = 32 * ks + 8 * (lane >> 4);
#pragma unroll
  for (int j = 0; j < 4; ++j) {
    float a0 = cval(n, k0 + 2 * j), a1 = cval(n, k0 + 2 * j + 1);
    uint32_t p0 = packhl(a0), p1 = packhl(a1);
    FAh[tid * 4 + j] = (p0 >> 16) | (p1 & 0xFFFF0000u);
    FAl[tid * 4 + j] = (p0 & 0xFFFFu) | (p1 << 16);
    float b0 = cval(k0 + 2 * j, n), b1 = cval(k0 + 2 * j + 1, n);
    uint32_t q0 = packhl(b0), q1 = packhl(b1);
    FTh[tid * 4 + j] = (q0 >> 16) | (q1 & 0xFFFF0000u);
    FTl[tid * 4 + j] = (q0 & 0xFFFFu) | (q1 << 16);
  }
}

// ---------- generic weight A-frag builder: W[D][K] row-major -> hi/lo frags ----------
// frag index: ((nt*(K/32) + ksl)*64 + lane)*4 + j ; lane holds W[16nt+(l&15)][32ksl+8(l>>4)+0..7]
__global__ void k_wfrag(const float* __restrict__ src, uint32_t* __restrict__ Fh,
                        uint32_t* __restrict__ Fl, int D, int K) {
  int tid = blockIdx.x * 256 + threadIdx.x;
  int nksl = K >> 5;
  int total = (D >> 4) * nksl * 64;
  if (tid >= total) return;
  int lane = tid & 63, fid = tid >> 6;
  int nt = fid / nksl, ksl = fid - nt * nksl;
  int d = 16 * nt + (lane & 15);
  int k0 = 32 * ksl + 8 * (lane >> 4);
#pragma unroll
  for (int j = 0; j < 4; ++j) {
    uint32_t p0 = packhl(src[d * K + k0 + 2 * j]);
    uint32_t p1 = packhl(src[d * K + k0 + 2 * j + 1]);
    Fh[tid * 4 + j] = (p0 >> 16) | (p1 & 0xFFFF0000u);
    Fl[tid * 4 + j] = (p0 & 0xFFFFu) | (p1 << 16);
  }
}

// ---------- generic weight transpose: src[D][C] -> dst[C][D] ----------
__global__ void k_wt(const float* __restrict__ src, float* __restrict__ dst, int D, int C) {
  int gid = blockIdx.x * 256 + threadIdx.x;
  if (gid >= D * C) return;
  int d = gid / C, c = gid % C;
  dst[c * D + d] = src[gid];
}

// ---------- fe transpose: [HW][96] -> [96][HW] ----------
__global__ __launch_bounds__(256) void k_tfe(const float* __restrict__ fe,
                                             float* __restrict__ fet) {
  __shared__ float tile[64 * 97];
  int hw0 = blockIdx.x * 64;
  int tid = threadIdx.x;
#pragma unroll
  for (int t = 0; t < 24; ++t) {
    int l = tid + t * 256;
    int r = l / 96, c0 = l % 96;
    tile[r * 97 + c0] = fe[((size_t)hw0 + r) * 96 + c0];
  }
  __syncthreads();
#pragma unroll
  for (int t = 0; t < 24; ++t) {
    int l = tid + t * 256;
    int c0 = l >> 6, r = l & 63;
    fet[(size_t)c0 * HW + hw0 + r] = tile[r * 97 + c0];
  }
}

// ---------- KC: depthwise 3x3 conv, float4 per thread, plane-major out ----------
__global__ __launch_bounds__(256) void kconv(
    const float* __restrict__ x, const float* __restrict__ dw_w,
    const float* __restrict__ dw_b, float* __restrict__ xc) {
  int gid = blockIdx.x * 256 + threadIdx.x;   // B*96*4096 = 3145728
  int p = gid >> 12;                          // plane b*96+c
  int q = gid & 4095;
  int h = q >> 5, w4 = (q & 31) << 2;
  int c = p % 96;
  const float* pw = dw_w + c * 9;
  const float* row = x + (size_t)p * HW + h * 128 + w4;
  bool tp = h > 0, bt = h < 127, lf = w4 > 0, rt = w4 < 124;
  float4 t_, m_, b_;
  float tl, tr, ml, mr, bl, br;
  m_ = *(const float4*)row;
  ml = lf ? row[-1] : 0.f;
  mr = rt ? row[4] : 0.f;
  if (tp) {
    t_ = *(const float4*)(row - 128);
    tl = lf ? row[-129] : 0.f;
    tr = rt ? row[-124] : 0.f;
  } else { t_ = make_float4(0.f, 0.f, 0.f, 0.f); tl = tr = 0.f; }
  if (bt) {
    b_ = *(const float4*)(row + 128);
    bl = lf ? row[127] : 0.f;
    br = rt ? row[132] : 0.f;
  } else { b_ = make_float4(0.f, 0.f, 0.f, 0.f); bl = br = 0.f; }
  float w0 = pw[0], w1 = pw[1], w2 = pw[2], w3 = pw[3], w4w = pw[4],
        w5 = pw[5], w6 = pw[6], w7 = pw[7], w8 = pw[8];
  float bias = dw_b[c];
  float4 o;
  o.x = tl * w0 + t_.x * w1 + t_.y * w2 + ml * w3 + m_.x * w4w + m_.y * w5 + bl * w6 + b_.x * w7 + b_.y * w8 + bias;
  o.y = t_.x * w0 + t_.y * w1 + t_.z * w2 + m_.x * w3 + m_.y * w4w + m_.z * w5 + b_.x * w6 + b_.y * w7 + b_.z * w8 + bias;
  o.z = t_.y * w0 + t_.z * w1 + t_.w * w2 + m_.y * w3 + m_.z * w4w + m_.w * w5 + b_.y * w6 + b_.z * w7 + b_.w * w8 + bias;
  o.w = t_.z * w0 + t_.w * w1 + tr * w2 + m_.z * w3 + m_.w * w4w + mr * w5 + b_.z * w6 + b_.w * w7 + br * w8 + bias;
  *(float4*)(xc + (size_t)p * HW + h * 128 + w4) = o;
}

// ---------- KL-MFMA: [B*HW,96] @ lin_w^T -> x1 planes + z planes ----------
// block = 64 positions, 4 waves; wave w owns n-tiles 3w..3w+2 (N=192)
__global__ __launch_bounds__(256) void klin_mfma(
    const float* __restrict__ xc, const uint32_t* __restrict__ WLh,
    const uint32_t* __restrict__ WLl, const float* __restrict__ lin_b,
    float* __restrict__ x1p, float* __restrict__ z) {
  __shared__ uint32_t Ds[64 * 102];   // [m][k], 26 KB
  const int tid = threadIdx.x;
  const int lane = tid & 63;
  const int w = tid >> 6;
  const int l15 = lane & 15, lg = lane >> 4;
  const int gp0 = blockIdx.x * 64;
  const int b = gp0 >> 14, hw0 = gp0 & 16383;

#pragma unroll
  for (int i = 0; i < 24; ++i) {      // stage xc -> Ds[m*102+k]
    int k = w + 4 * i;
    float v = xc[((size_t)(b * 96 + k)) * HW + hw0 + lane];
    Ds[lane * 102 + k] = packhl(v);
  }
  __syncthreads();

  f32x4 acc[3][4];
#pragma unroll
  for (int nt = 0; nt < 3; ++nt) {
    float bv[4];
#pragma unroll
    for (int r = 0; r < 4; ++r) bv[r] = lin_b[16 * (3 * w + nt) + 4 * lg + r];
#pragma unroll
    for (int mt = 0; mt < 4; ++mt)
#pragma unroll
      for (int r = 0; r < 4; ++r) acc[nt][mt][r] = bv[r];
  }

#pragma unroll
  for (int ksl = 0; ksl < 3; ++ksl) {
    s8bf Dhi[4], Dlo[4];
#pragma unroll
    for (int mt = 0; mt < 4; ++mt) {
      const uint32_t* p = Ds + (16 * mt + l15) * 102 + 32 * ksl + 8 * lg;
      uint32_t wv[8];
      *(uint2*)&wv[0] = *(const uint2*)(p);
      *(uint2*)&wv[2] = *(const uint2*)(p + 2);
      *(uint2*)&wv[4] = *(const uint2*)(p + 4);
      *(uint2*)&wv[6] = *(const uint2*)(p + 6);
      unpack8(wv, Dhi[mt], Dlo[mt]);
    }
#pragma unroll
    for (int nt = 0; nt < 3; ++nt) {
      int base = (((3 * w + nt) * 3 + ksl) * 64 + lane) * 4;
      FragU H, L;
      *(uint4*)H.u = *(const uint4*)(WLh + base);
      *(uint4*)L.u = *(const uint4*)(WLl + base);
#pragma unroll
      for (int mt = 0; mt < 4; ++mt) {
        acc[nt][mt] = __builtin_amdgcn_mfma_f32_16x16x32_bf16(H.s, Dhi[mt], acc[nt][mt], 0, 0, 0);
        acc[nt][mt] = __builtin_amdgcn_mfma_f32_16x16x32_bf16(H.s, Dlo[mt], acc[nt][mt], 0, 0, 0);
        acc[nt][mt] = __builtin_amdgcn_mfma_f32_16x16x32_bf16(L.s, Dhi[mt], acc[nt][mt], 0, 0, 0);
      }
    }
  }
#pragma unroll
  for (int nt = 0; nt < 3; ++nt) {
    int d0 = 16 * (3 * w + nt) + 4 * lg;
#pragma unroll
    for (int mt = 0; mt < 4; ++mt) {
#pragma unroll
      for (int r = 0; r < 4; ++r) {
        int d = d0 + r;
        if (d < 96)
          x1p[((size_t)(b * 96 + d)) * HW + hw0 + 16 * mt + l15] = acc[nt][mt][r];
        else
          z[((size_t)(d - 96)) * BHW + gp0 + 16 * mt + l15] = acc[nt][mt][r];
      }
    }
  }
}

// ---------- K3: outline_feat transpose to plane-major + mean over B ----------
__global__ __launch_bounds__(256) void k3_transpose_mean(
    const float* __restrict__ of, float* __restrict__ ofp, float* __restrict__ cmU) {
  __shared__ float tile[64 * 97];
  int hw0 = blockIdx.x * 64;
  int tid = threadIdx.x;
  float sum[24];
#pragma unroll
  for (int t = 0; t < 24; ++t) sum[t] = 0.f;
  for (int b = 0; b < 8; ++b) {
    __syncthreads();
#pragma unroll
    for (int t = 0; t < 24; ++t) {
      int l = tid + t * 256;
      int r = l / 96, c0 = l % 96;
      tile[r * 97 + c0] = of[((size_t)b * 16384 + hw0 + r) * 96 + c0];
    }
    __syncthreads();
#pragma unroll
    for (int t = 0; t < 24; ++t) {
      int l = tid + t * 256;
      int c0 = l >> 6, r = l & 63;
      float v = tile[r * 97 + c0];
      sum[t] += v;
      ofp[(size_t)(b * 96 + c0) * HW + hw0 + r] = v;
    }
  }
#pragma unroll
  for (int t = 0; t < 24; ++t) {
    int l = tid + t * 256;
    int c0 = l >> 6, r = l & 63;
    cmU[(size_t)c0 * HW + hw0 + r] = sum[t] * 0.125f;
  }
}

// ---------- K3b: k = relu((fet+otm)@k_w^T + k_b); P1 = exp(-e*k) ----------
__global__ __launch_bounds__(256) void k3b_kgemm(
    const float* __restrict__ fet, const float* __restrict__ otm,
    const float* __restrict__ kT, const float* __restrict__ kb,
    const float* __restrict__ ee, float* __restrict__ P1) {
  int tid = threadIdx.x;
  int lane = tid & 63;
  int n0 = __builtin_amdgcn_readfirstlane((tid >> 6) * 24);
  int row = blockIdx.x * 64 + lane;           // 256 blocks
  float acc[24];
#pragma unroll
  for (int j = 0; j < 24; ++j) acc[j] = kb[n0 + j];
#pragma unroll 4
  for (int c = 0; c < 96; ++c) {
    float a = fet[(size_t)c * HW + row] + otm[(size_t)c * HW + row];
    const float* wr = kT + c * 96 + n0;
#pragma unroll
    for (int j = 0; j < 24; ++j) acc[j] = fmaf(a, wr[j], acc[j]);
  }
  float er = ee[row];
#pragma unroll
  for (int j = 0; j < 24; ++j)
    P1[(size_t)(n0 + j) * HW + row] = expf(-er * fmaxf(acc[j], 0.f));
}

// ---------- MFMA heat pass (unchanged from R5) ----------
template <bool DATA_A>
__device__ __forceinline__ void heat_step(
    const uint32_t* __restrict__ Fh, const uint32_t* __restrict__ Fl,
    const uint32_t* __restrict__ Ds, f32x4 (&acc)[4][4], int wm, int wn, int lane) {
  const int l15 = lane & 15, lg = lane >> 4;
  const int wd = DATA_A ? wm : wn;
  const int wf = DATA_A ? wn : wm;
#pragma unroll
  for (int ksl = 0; ksl < 4; ++ksl) {
    s8bf Dhi[4], Dlo[4], Fhi[4], Flo[4];
#pragma unroll
    for (int t = 0; t < 4; ++t) {
      const uint32_t* p = Ds + (64 * wd + 16 * t + l15) * 130 + 32 * ksl + 8 * lg;
      uint32_t wv[8];
      *(uint2*)&wv[0] = *(const uint2*)(p);
      *(uint2*)&wv[2] = *(const uint2*)(p + 2);
      *(uint2*)&wv[4] = *(const uint2*)(p + 4);
      *(uint2*)&wv[6] = *(const uint2*)(p + 6);
      unpack8(wv, Dhi[t], Dlo[t]);
    }
#pragma unroll
    for (int t = 0; t < 4; ++t) {
      int base = (((4 * wf + t) * 4 + ksl) * 64 + lane) * 4;
      FragU H, L;
      *(uint4*)H.u = *(const uint4*)(Fh + base);
      *(uint4*)L.u = *(const uint4*)(Fl + base);
      Fhi[t] = H.s; Flo[t] = L.s;
    }
    const s8bf* Ah = DATA_A ? Dhi : Fhi;
    const s8bf* Al = DATA_A ? Dlo : Flo;
    const s8bf* Bh = DATA_A ? Fhi : Dhi;
    const s8bf* Bl = DATA_A ? Flo : Dlo;
#pragma unroll
    for (int mi = 0; mi < 4; ++mi)
#pragma unroll
      for (int ni = 0; ni < 4; ++ni)
        acc[mi][ni] = __builtin_amdgcn_mfma_f32_16x16x32_bf16(Ah[mi], Bh[ni], acc[mi][ni], 0, 0, 0);
#pragma unroll
    for (int mi = 0; mi < 4; ++mi)
#pragma unroll
      for (int ni = 0; ni < 4; ++ni)
        acc[mi][ni] = __builtin_amdgcn_mfma_f32_16x16x32_bf16(Ah[mi], Bl[ni], acc[mi][ni], 0, 0, 0);
#pragma unroll
    for (int mi = 0; mi < 4; ++mi)
#pragma unroll
      for (int ni = 0; ni < 4; ++ni)
        acc[mi][ni] = __builtin_amdgcn_mfma_f32_16x16x32_bf16(Al[mi], Bh[ni], acc[mi][ni], 0, 0, 0);
  }
}

__global__ __launch_bounds__(256, 2) void heat_mfma(
    float* bufA, float* bufB, const float* __restrict__ P,
    const uint32_t* __restrict__ FAh, const uint32_t* __restrict__ FAl,
    const uint32_t* __restrict__ FTh, const uint32_t* __restrict__ FTl, int Ceff) {
  __shared__ uint32_t Ds[128 * 130];
  const int tid = threadIdx.x;
  const int lane = tid & 63;
  const int w = tid >> 6;
  const int wm = w >> 1, wn = w & 1;
  const int plane = blockIdx.x;
  const int b = plane / Ceff, c = plane % Ceff;
  float* Ug = (c < 96) ? (bufA + (size_t)(b * 96 + c) * HW)
                       : (bufB + (size_t)(b * 96 + (c - 96)) * HW);
  const float* Pp = P + (size_t)c * HW;

  {
    int col = tid & 127, r0 = tid >> 7;
#pragma unroll
    for (int i = 0; i < 64; ++i) {
      int row = r0 + 2 * i;
      Ds[col * 130 + row] = packhl(Ug[row * 128 + col]);
    }
  }
  __syncthreads();

  f32x4 acc[4][4];
  const f32x4 zero4 = {0.f, 0.f, 0.f, 0.f};

#pragma unroll
  for (int mi = 0; mi < 4; ++mi)
#pragma unroll
    for (int ni = 0; ni < 4; ++ni) acc[mi][ni] = zero4;
  heat_step<false>(FAh, FAl, Ds, acc, wm, wn, lane);
  __syncthreads();
#pragma unroll
  for (int mi = 0; mi < 4; ++mi)
#pragma unroll
    for (int ni = 0; ni < 4; ++ni)
#pragma unroll
      for (int r = 0; r < 4; ++r)
        Ds[(64 * wm + 16 * mi + 4 * (lane >> 4) + r) * 130 + 64 * wn + 16 * ni + (lane & 15)] =
            packhl(acc[mi][ni][r]);
  __syncthreads();

#pragma unroll
  for (int mi = 0; mi < 4; ++mi)
#pragma unroll
    for (int ni = 0; ni < 4; ++ni) acc[mi][ni] = zero4;
  heat_step<true>(FAh, FAl, Ds, acc, wm, wn, lane);
#pragma unroll
  for (int mi = 0; mi < 4; ++mi)
#pragma unroll
    for (int ni = 0; ni < 4; ++ni) {
      int row = 64 * wm + 16 * mi + 4 * (lane >> 4);
      int col = 64 * wn + 16 * ni + (lane & 15);
#pragma unroll
      for (int r = 0; r < 4; ++r)
        acc[mi][ni][r] *= Pp[(row + r) * 128 + col];
    }
  __syncthreads();
#pragma unroll
  for (int mi = 0; mi < 4; ++mi)
#pragma unroll
    for (int ni = 0; ni < 4; ++ni)
#pragma unroll
      for (int r = 0; r < 4; ++r)
        Ds[(64 * wn + 16 * ni + (lane & 15)) * 130 + 64 * wm + 16 * mi + 4 * (lane >> 4) + r] =
            packhl(acc[mi][ni][r]);
  __syncthreads();

#pragma unroll
  for (int mi = 0; mi < 4; ++mi)
#pragma unroll
    for (int ni = 0; ni < 4; ++ni) acc[mi][ni] = zero4;
  heat_step<false>(FTh, FTl, Ds, acc, wm, wn, lane);
  __syncthreads();
#pragma unroll
  for (int mi = 0; mi < 4; ++mi)
#pragma unroll
    for (int ni = 0; ni < 4; ++ni)
#pragma unroll
      for (int r = 0; r < 4; ++r)
        Ds[(64 * wm + 16 * mi + 4 * (lane >> 4) + r) * 130 + 64 * wn + 16 * ni + (lane & 15)] =
            packhl(acc[mi][ni][r]);
  __syncthreads();

#pragma unroll
  for (int mi = 0; mi < 4; ++mi)
#pragma unroll
    for (int ni = 0; ni < 4; ++ni) acc[mi][ni] = zero4;
  heat_step<true>(FTh, FTl, Ds, acc, wm, wn, lane);
#pragma unroll
  for (int mi = 0; mi < 4; ++mi)
#pragma unroll
    for (int ni = 0; ni < 4; ++ni) {
      int row = 64 * wm + 16 * mi + 4 * (lane >> 4);
      int col = 64 * wn + 16 * ni + (lane & 15);
#pragma unroll
      for (int r = 0; r < 4; ++r)
        Ug[(row + r) * 128 + col] = acc[mi][ni][r];
    }
}

// ---------- K5: catmean lower half = mean_b(y1) ----------
__global__ void k5_mean(const float* __restrict__ x1p, float* __restrict__ cmL) {
  int idx = blockIdx.x * 256 + threadIdx.x;
  int c = idx >> 14, s = idx & 16383;
  float sum = 0.f;
#pragma unroll
  for (int b = 0; b < 8; ++b) sum += x1p[(size_t)(b * 96 + c) * HW + s];
  cmL[idx] = sum * 0.125f;
}

// ---------- K6: skfeat = catmean @ lin2_w^T + lin2_b ----------
__global__ __launch_bounds__(256) void k6_skf(
    const float* __restrict__ cm, const float* __restrict__ w2T,
    const float* __restrict__ b2, float* __restrict__ skf) {
  int tid = threadIdx.x;
  int lane = tid & 63;
  int row = (blockIdx.x >> 1) * 64 + lane;    // 512 blocks
  int n0 = __builtin_amdgcn_readfirstlane((blockIdx.x & 1) * 96 + (tid >> 6) * 24);
  float acc[24];
#pragma unroll
  for (int j = 0; j < 24; ++j) acc[j] = b2[n0 + j];
#pragma unroll 4
  for (int k = 0; k < 192; ++k) {
    float a = cm[(size_t)k * HW + row];
    const float* wr = w2T + k * 192 + n0;
#pragma unroll
    for (int j = 0; j < 24; ++j) acc[j] = fmaf(a, wr[j], acc[j]);
  }
#pragma unroll
  for (int j = 0; j < 24; ++j) skf[(size_t)(n0 + j) * HW + row] = acc[j];
}

// ---------- K7: k2 = relu(skf@k2_w^T + k2_b); P2 = exp(-e*k2) ----------
__global__ __launch_bounds__(256) void k7_k2(
    const float* __restrict__ skf, const float* __restrict__ w2T,
    const float* __restrict__ b2, const float* __restrict__ ee,
    float* __restrict__ P2) {
  int tid = threadIdx.x;
  int lane = tid & 63;
  int row = (blockIdx.x >> 1) * 64 + lane;    // 512 blocks
  int n0 = __builtin_amdgcn_readfirstlane((blockIdx.x & 1) * 96 + (tid >> 6) * 24);
  float acc[24];
#pragma unroll
  for (int j = 0; j < 24; ++j) acc[j] = b2[n0 + j];
#pragma unroll 4
  for (int k = 0; k < 192; ++k) {
    float a = skf[(size_t)k * HW + row];
    const float* wr = w2T + k * 192 + n0;
#pragma unroll
    for (int j = 0; j < 24; ++j) acc[j] = fmaf(a, wr[j], acc[j]);
  }
  float er = ee[row];
#pragma unroll
  for (int j = 0; j < 24; ++j)
    P2[(size_t)(n0 + j) * HW + row] = expf(-er * fmaxf(acc[j], 0.f));
}

// ---------- K9-MFMA: lin3 + LN + silu(z)* + out GEMM ----------
// block = 64 positions, 4 waves as 2x2: wn = n-half, wm = m-half
__global__ __launch_bounds__(256) void k9_mfma(
    const float* __restrict__ y1, const float* __restrict__ y2,
    const float* __restrict__ z,
    const uint32_t* __restrict__ W3h, const uint32_t* __restrict__ W3l,
    const float* __restrict__ lin3b,
    const float* __restrict__ lng, const float* __restrict__ lnb,
    const uint32_t* __restrict__ WOh, const uint32_t* __restrict__ WOl,
    const float* __restrict__ outb, float* __restrict__ out) {
  __shared__ uint32_t Ds[64 * 194];           // [m][k=192], 48.5 KB (Ds2 aliases)
  __shared__ float lnred[2][2][16][2][2];     // [wn][wm][l15][j][{sum,sumsq}]
  const int tid = threadIdx.x;
  const int lane = tid & 63;
  const int w = tid >> 6;
  const int wn = w >> 1, wm = w & 1;
  const int l15 = lane & 15, lg = lane >> 4;
  const int gp0 = blockIdx.x * 64;
  const int b = gp0 >> 14, hw0 = gp0 & 16383;

#pragma unroll
  for (int i = 0; i < 48; ++i) {      // stage y1|y2 -> Ds[m*194+k]
    int k = w + 4 * i;
    const float* src = (k < 96) ? (y1 + ((size_t)(b * 96 + k)) * HW)
                                : (y2 + ((size_t)(b * 96 + k - 96)) * HW);
    Ds[lane * 194 + k] = packhl(src[hw0 + lane]);
  }
  __syncthreads();

  // phase A: t = y @ lin3^T  (nt = 3wn+i, mt = 2wm+j)
  f32x4 acc[3][2];
#pragma unroll
  for (int i = 0; i < 3; ++i) {
    float bv[4];
#pragma unroll
    for (int r = 0; r < 4; ++r) bv[r] = lin3b[16 * (3 * wn + i) + 4 * lg + r];
#pragma unroll
    for (int j = 0; j < 2; ++j)
#pragma unroll
      for (int r = 0; r < 4; ++r) acc[i][j][r] = bv[r];
  }
#pragma unroll
  for (int ksl = 0; ksl < 6; ++ksl) {
    s8bf Dhi[2], Dlo[2];
#pragma unroll
    for (int j = 0; j < 2; ++j) {
      const uint32_t* p = Ds + (16 * (2 * wm + j) + l15) * 194 + 32 * ksl + 8 * lg;
      uint32_t wv[8];
      *(uint2*)&wv[0] = *(const uint2*)(p);
      *(uint2*)&wv[2] = *(const uint2*)(p + 2);
      *(uint2*)&wv[4] = *(const uint2*)(p + 4);
      *(uint2*)&wv[6] = *(const uint2*)(p + 6);
      unpack8(wv, Dhi[j], Dlo[j]);
    }
#pragma unroll
    for (int i = 0; i < 3; ++i) {
      int base = (((3 * wn + i) * 6 + ksl) * 64 + lane) * 4;
      FragU H, L;
      *(uint4*)H.u = *(const uint4*)(W3h + base);
      *(uint4*)L.u = *(const uint4*)(W3l + base);
#pragma unroll
      for (int j = 0; j < 2; ++j) {
        acc[i][j] = __builtin_amdgcn_mfma_f32_16x16x32_bf16(H.s, Dhi[j], acc[i][j], 0, 0, 0);
        acc[i][j] = __builtin_amdgcn_mfma_f32_16x16x32_bf16(H.s, Dlo[j], acc[i][j], 0, 0, 0);
        acc[i][j] = __builtin_amdgcn_mfma_f32_16x16x32_bf16(L.s, Dhi[j], acc[i][j], 0, 0, 0);
      }
    }
  }

  // LN stats per m-col (cross-lane over lg, cross-wave over wn)
#pragma unroll
  for (int j = 0; j < 2; ++j) {
    float a = 0.f, q = 0.f;
#pragma unroll
    for (int i = 0; i < 3; ++i)
#pragma unroll
      for (int r = 0; r < 4; ++r) { float v = acc[i][j][r]; a += v; q = fmaf(v, v, q); }
    a += __shfl_xor(a, 16); a += __shfl_xor(a, 32);
    q += __shfl_xor(q, 16); q += __shfl_xor(q, 32);
    if (lg == 0) { lnred[wn][wm][l15][j][0] = a; lnred[wn][wm][l15][j][1] = q; }
  }
  __syncthreads();    // also guarantees all Ds reads complete (Ds2 aliases Ds)
  float mu[2], inv[2];
#pragma unroll
  for (int j = 0; j < 2; ++j) {
    float a = lnred[0][wm][l15][j][0] + lnred[1][wm][l15][j][0];
    float q = lnred[0][wm][l15][j][1] + lnred[1][wm][l15][j][1];
    float m_ = a * (1.f / 96.f);
    float v_ = q * (1.f / 96.f) - m_ * m_;
    mu[j] = m_;
    inv[j] = rsqrtf(fmaxf(v_, 0.f) + 1e-5f);
  }

  // activation: LN affine * silu(z); pack into Ds2[m*98 + d]
  uint32_t* Ds2 = Ds;
#pragma unroll
  for (int j = 0; j < 2; ++j) {
    int mcol = 16 * (2 * wm + j) + l15;
    int gm = gp0 + mcol;
#pragma unroll
    for (int i = 0; i < 3; ++i) {
      int d0 = 16 * (3 * wn + i) + 4 * lg;
#pragma unroll
      for (int r = 0; r < 4; ++r) {
        int d = d0 + r;
        float zv = z[(size_t)d * BHW + gm];
        float sil = zv / (1.f + expf(-zv));
        float u = (acc[i][j][r] - mu[j]) * inv[j] * lng[d] + lnb[d];
        Ds2[mcol * 98 + d] = packhl(u * sil);
      }
    }
  }
  __syncthreads();

  // phase B: out = t_act @ out_w^T  (K=96, N=96)
  f32x4 acc2[3][2];
#pragma unroll
  for (int i = 0; i < 3; ++i) {
    float bv[4];
#pragma unroll
    for (int r = 0; r < 4; ++r) bv[r] = outb[16 * (3 * wn + i) + 4 * lg + r];
#pragma unroll
    for (int j = 0; j < 2; ++j)
#pragma unroll
      for (int r = 0; r < 4; ++r) acc2[i][j][r] = bv[r];
  }
#pragma unroll
  for (int ksl = 0; ksl < 3; ++ksl) {
    s8bf Dhi[2], Dlo[2];
#pragma unroll
    for (int j = 0; j < 2; ++j) {
      const uint32_t* p = Ds2 + (16 * (2 * wm + j) + l15) * 98 + 32 * ksl + 8 * lg;
      uint32_t wv[8];
      *(uint2*)&wv[0] = *(const uint2*)(p);
      *(uint2*)&wv[2] = *(const uint2*)(p + 2);
      *(uint2*)&wv[4] = *(const uint2*)(p + 4);
      *(uint2*)&wv[6] = *(const uint2*)(p + 6);
      unpack8(wv, Dhi[j], Dlo[j]);
    }
#pragma unroll
    for (int i = 0; i < 3; ++i) {
      int base = (((3 * wn + i) * 3 + ksl) * 64 + lane) * 4;
      FragU H, L;
      *(uint4*)H.u = *(const uint4*)(WOh + base);
      *(uint4*)L.u = *(const uint4*)(WOl + base);
#pragma unroll
      for (int j = 0; j < 2; ++j) {
        acc2[i][j] = __builtin_amdgcn_mfma_f32_16x16x32_bf16(H.s, Dhi[j], acc2[i][j], 0, 0, 0);
        acc2[i][j] = __builtin_amdgcn_mfma_f32_16x16x32_bf16(H.s, Dlo[j], acc2[i][j], 0, 0, 0);
        acc2[i][j] = __builtin_amdgcn_mfma_f32_16x16x32_bf16(L.s, Dhi[j], acc2[i][j], 0, 0, 0);
      }
    }
  }
#pragma unroll
  for (int i = 0; i < 3; ++i) {
    int d0 = 16 * (3 * wn + i) + 4 * lg;
#pragma unroll
    for (int j = 0; j < 2; ++j) {
      int hw = hw0 + 16 * (2 * wm + j) + l15;
#pragma unroll
      for (int r = 0; r < 4; ++r)
        out[((size_t)(b * 96 + d0 + r)) * HW + hw] = acc2[i][j][r];
    }
  }
}

extern "C" void kernel_launch(void* const* d_in, const int* in_sizes, int n_in,
                              void* d_out, int out_size, void* d_ws, size_t ws_size,
                              hipStream_t stream) {
  const float* x      = (const float*)d_in[0];
  const float* fe     = (const float*)d_in[1];
  const float* of     = (const float*)d_in[2];
  const float* dw_w   = (const float*)d_in[3];
  const float* dw_b   = (const float*)d_in[4];
  const float* lin_w  = (const float*)d_in[5];
  const float* lin_b  = (const float*)d_in[6];
  const float* k_w    = (const float*)d_in[7];
  const float* k_b    = (const float*)d_in[8];
  const float* lin2_w = (const float*)d_in[9];
  const float* lin2_b = (const float*)d_in[10];
  const float* k2_w   = (const float*)d_in[11];
  const float* k2_b   = (const float*)d_in[12];
  const float* lin3_w = (const float*)d_in[13];
  const float* lin3_b = (const float*)d_in[14];
  const float* ln_g   = (const float*)d_in[15];
  const float* ln_b   = (const float*)d_in[16];
  const float* out_w  = (const float*)d_in[17];
  const float* out_b  = (const float*)d_in[18];
  float* out = (float*)d_out;

  float* ws    = (float*)d_ws;
  float* x1p   = ws;                      // [B][96][HW]  (x1 -> y1 -> y2 low)
  float* z     = x1p   + 12582912;        // [96][B*HW] plane-major
  float* ofp   = z     + 12582912;        // [B][96][HW]  (xc first, then outline planes)
  float* cm    = ofp   + 12582912;        // [192][HW]
  float* skf   = cm    + 3145728;         // [192][HW]
  float* P1    = skf   + 3145728;         // [96][HW]
  float* P2    = P1    + 1572864;         // [192][HW]
  float* cc    = P2    + 3145728;         // [128][128] (unused by heat now)
  float* ee    = cc    + 16384;           // [128][128]
  float* linT  = ee    + 16384;           // (unused)
  float* kT    = linT  + 18432;           // [96][96]
  float* lin2T = kT    + 9216;            // [192][192]
  float* k2T   = lin2T + 36864;           // [192][192]
  float* lin3T = k2T   + 36864;           // (unused)
  float* outT  = lin3T + 18432;           // (unused)
  float* fet   = outT  + 9216;            // [96][HW] = 1572864
  uint32_t* FAh = (uint32_t*)(fet + 1572864);  // 8192 u32 each
  uint32_t* FAl = FAh + 8192;
  uint32_t* FTh = FAl + 8192;
  uint32_t* FTl = FTh + 8192;
  uint32_t* WLh = FTl + 8192;             // lin frags:  12x3x64x4 = 9216 u32
  uint32_t* WLl = WLh + 9216;
  uint32_t* W3h = WLl + 9216;             // lin3 frags: 6x6x64x4 = 9216
  uint32_t* W3l = W3h + 9216;
  uint32_t* WOh = W3l + 9216;             // out frags:  6x3x64x4 = 4608
  uint32_t* WOl = WOh + 4608;
  float* xc    = ofp;                     // aliases ofp: dead after klin, before k3
  (void)in_sizes; (void)n_in; (void)out_size; (void)ws_size;

  k0_tables<<<64, 256, 0, stream>>>(cc, ee);
  k0_frags<<<8, 256, 0, stream>>>(FAh, FAl, FTh, FTl);
  k_wfrag<<<9, 256, 0, stream>>>(lin_w, WLh, WLl, 192, 96);
  k_wfrag<<<9, 256, 0, stream>>>(lin3_w, W3h, W3l, 96, 192);
  k_wfrag<<<5, 256, 0, stream>>>(out_w, WOh, WOl, 96, 96);
  k_wt<<<36, 256, 0, stream>>>(k_w, kT, 96, 96);
  k_wt<<<144, 256, 0, stream>>>(lin2_w, lin2T, 192, 192);
  k_wt<<<144, 256, 0, stream>>>(k2_w, k2T, 192, 192);
  k_tfe<<<256, 256, 0, stream>>>(fe, fet);

  kconv<<<12288, 256, 0, stream>>>(x, dw_w, dw_b, xc);
  klin_mfma<<<2048, 256, 0, stream>>>(xc, WLh, WLl, lin_b, x1p, z);
  k3_transpose_mean<<<256, 256, 0, stream>>>(of, ofp, cm + (size_t)96 * HW);
  k3b_kgemm<<<256, 256, 0, stream>>>(fet, cm + (size_t)96 * HW, kT, k_b, ee, P1);
  heat_mfma<<<768, 256, 0, stream>>>(x1p, x1p, P1, FAh, FAl, FTh, FTl, 96);
  k5_mean<<<6144, 256, 0, stream>>>(x1p, cm);
  k6_skf<<<512, 256, 0, stream>>>(cm, lin2T, lin2_b, skf);
  k7_k2<<<512, 256, 0, stream>>>(skf, k2T, k2_b, ee, P2);
  heat_mfma<<<1536, 256, 0, stream>>>(x1p, ofp, P2, FAh, FAl, FTh, FTl, 192);
  k9_mfma<<<2048, 256, 0, stream>>>(x1p, ofp, z, W3h, W3l, lin3_b, ln_g, ln_b,
                                    WOh, WOl, out_b, out);
}